// Round 5
// baseline (2243.891 us; speedup 1.0000x reference)
//
#include <hip/hip_runtime.h>

typedef unsigned short ushort_t;
typedef unsigned int u32;
typedef float f32x4 __attribute__((ext_vector_type(4)));
typedef float f32x2 __attribute__((ext_vector_type(2)));
typedef __bf16 bf16x8 __attribute__((ext_vector_type(8)));

#define B_ 8
#define L_ 4096
#define D_ 384
#define DI_ 768
#define S_ 16
#define NC_ 40
#define ML_ (B_*L_)   // 32768 rows
#define NCHUNK 32
#define CL 128        // chunk length (L_/NCHUNK)
#define STG 108       // rows of xdbl staged in LDS (24192 B -> 24576 alloc; 6 blocks/CU)

// ---------------- workspace layout (bytes) ----------------
// ~154 MB total. Aliasing:
//   XN lives in XC region (dead after gemm1, before conv writes XC);
//   XDBL lives at start of XP region (XP dead after conv);
//   FX (chunk summaries, 38.5 MB) lives in XP region after XDBL.
constexpr size_t au(size_t x){ return (x + 255) & ~size_t(255); }
constexpr size_t O_FLAG = 0;                                   // int
constexpr size_t O_LNW  = 256;                                 // 384 f32
constexpr size_t O_CONVW= au(O_LNW  + 384*4);                  // 3072 f32
constexpr size_t O_CONVB= au(O_CONVW+ 3072*4);                 // 768 f32
constexpr size_t O_WDT  = au(O_CONVB+ 768*4);                  // 18432 f32
constexpr size_t O_DTB  = au(O_WDT  + 18432*4);                // 768 f32
constexpr size_t O_A    = au(O_DTB  + 768*4);                  // 12288 f32 (A = -exp(A_log)*log2e)
constexpr size_t O_DSKIP= au(O_A    + 12288*4);                // 768 f32
constexpr size_t O_WOUT = au(O_DSKIP+ 768*4);                  // 294912 f32
constexpr size_t O_WFC  = au(O_WOUT + 294912*4);               // 98304 f32
constexpr size_t O_BFC  = au(O_WFC  + 98304*4);                // 256 f32
constexpr size_t O_GAM  = au(O_BFC  + 256*4);
constexpr size_t O_BET  = au(O_GAM  + 256*4);
constexpr size_t O_WCLS = au(O_BET  + 256*4);                  // 10240 f32
constexpr size_t O_BCLS = au(O_WCLS + 10240*4);                // 40 f32
constexpr size_t O_XMEAN= au(O_BCLS + 40*4);                   // 8*384 f32 (atomic acc, zeroed in prep)
constexpr size_t O_YMEAN= au(O_XMEAN+ 3072*4);                 // 8*768 f32
constexpr size_t O_H    = au(O_YMEAN+ 6144*4);                 // 8*256 f32
constexpr size_t O_WINT = au(O_H    + 2048*4);                 // W_in^T  [1536][384] bf16
constexpr size_t O_WXT  = au(O_WINT + (size_t)589824*2);       // W_xproj^T padded [64][768] bf16
constexpr size_t O_XP   = au(O_WXT  + (size_t)49152*2);        // [32768][768] bf16
constexpr size_t O_XDBL = O_XP;                                // alias: [32768][56] f32 (after conv)
constexpr size_t O_FX   = au(O_XDBL + (size_t)ML_*56*4);       // [b][c][49][768] f32 chunk summaries
constexpr size_t FX_SZ  = (size_t)B_*NCHUNK*49*768*4;          // 38.5 MB
constexpr size_t O_Z    = au(O_XP   + (size_t)ML_*768*2);      // [32768][768] bf16 (holds silu(z))
constexpr size_t O_XCU  = au(O_Z    + (size_t)ML_*768*2);      // union region, 50.3 MB
constexpr size_t O_XN   = O_XCU;                               // [32768][384] bf16 (dead after gemm1)
constexpr size_t O_XC   = O_XCU;                               // [32768][768] bf16
constexpr size_t WS_NEED= O_XCU + (size_t)ML_*768*2;           // ~154 MB
static_assert(O_FX + FX_SZ <= O_Z, "FX must fit in dead XP tail");

// ---------------- helpers ----------------
__device__ inline float bf2f(ushort_t u){ return __uint_as_float(((u32)u) << 16); }
__device__ inline ushort_t f2bf(float f){
    u32 x = __float_as_uint(f);
    u32 r = (x + 0x7fffu + ((x >> 16) & 1u)) >> 16;   // RNE
    return (ushort_t)r;
}
__device__ inline float ldf(const void* p, long i, int flag){
    return flag ? bf2f(((const ushort_t*)p)[i]) : ((const float*)p)[i];
}
__device__ inline ushort_t ldbf(const void* p, long i, int flag){
    return flag ? ((const ushort_t*)p)[i] : f2bf(((const float*)p)[i]);
}
__device__ inline float sigm(float v){ return 1.f / (1.f + __expf(-v)); }

__device__ inline void gload_lds16(const void* g, void* l){
    __builtin_amdgcn_global_load_lds(
        (const __attribute__((address_space(1))) u32*)g,
        (__attribute__((address_space(3))) u32*)l, 16, 0, 0);
}

struct Ptrs { const void* p[17]; };

// ---------------- k0: dtype detect ----------------
__global__ void k_detect(const void* x, char* ws){
    __shared__ float s[256];
    int tid = threadIdx.x;
    s[tid] = fabsf(bf2f(((const ushort_t*)x)[tid]));
    __syncthreads();
    for (int st = 128; st > 0; st >>= 1){
        if (tid < st) s[tid] = fmaxf(s[tid], s[tid + st]);
        __syncthreads();
    }
    if (tid == 0) *(int*)(ws + O_FLAG) = (s[0] < 1e4f) ? 1 : 0;
}

// ---------------- k1: weight prep ----------------
#define N_PREP 1082792L
__global__ __launch_bounds__(256) void k_prep(Ptrs ps, char* ws){
    const int flag = *(const int*)(ws + O_FLAG);
    long o = (long)blockIdx.x * 256 + threadIdx.x;
    if (o < 384){ ((float*)(ws+O_LNW))[o]  = ldf(ps.p[1],o,flag); return; }  o -= 384;
    if (o < 3072){ ((float*)(ws+O_CONVW))[o]= ldf(ps.p[3],o,flag); return; } o -= 3072;
    if (o < 768){ ((float*)(ws+O_CONVB))[o]= ldf(ps.p[4],o,flag); return; }  o -= 768;
    if (o < 18432){ ((float*)(ws+O_WDT))[o]= ldf(ps.p[6],o,flag); return; }  o -= 18432;
    if (o < 768){ ((float*)(ws+O_DTB))[o]  = ldf(ps.p[7],o,flag); return; }  o -= 768;
    if (o < 768){ ((float*)(ws+O_DSKIP))[o]= ldf(ps.p[9],o,flag); return; }  o -= 768;
    if (o < 294912){ ((float*)(ws+O_WOUT))[o]= ldf(ps.p[10],o,flag); return; } o -= 294912;
    if (o < 98304){ ((float*)(ws+O_WFC))[o]= ldf(ps.p[11],o,flag); return; } o -= 98304;
    if (o < 256){ ((float*)(ws+O_BFC))[o]  = ldf(ps.p[12],o,flag); return; } o -= 256;
    if (o < 256){ ((float*)(ws+O_GAM))[o]  = ldf(ps.p[13],o,flag); return; } o -= 256;
    if (o < 256){ ((float*)(ws+O_BET))[o]  = ldf(ps.p[14],o,flag); return; } o -= 256;
    if (o < 10240){ ((float*)(ws+O_WCLS))[o]= ldf(ps.p[15],o,flag); return; } o -= 10240;
    if (o < 40){ ((float*)(ws+O_BCLS))[o]  = ldf(ps.p[16],o,flag); return; } o -= 40;
    // A = -exp(A_log) * log2(e)   (scan uses exp2)
    if (o < 12288){ ((float*)(ws+O_A))[o]  = -__expf(ldf(ps.p[8],o,flag)) * 1.4426950408889634f; return; } o -= 12288;
    if (o < 589824){                     // W_in [384,1536] -> WinT [1536][384]
        long n = o / 384, k = o % 384;
        ((ushort_t*)(ws+O_WINT))[o] = ldbf(ps.p[2], k*1536 + n, flag); return;
    } o -= 589824;
    if (o < 49152){                      // W_xproj [768,56] -> WxT [64][768], zero-pad n>=56
        long n = o / 768, k = o % 768;
        ((ushort_t*)(ws+O_WXT))[o] = (n < 56) ? ldbf(ps.p[5], k*56 + n, flag) : (ushort_t)0;
        return;
    } o -= 49152;
    if (o < 3072){ ((float*)(ws+O_XMEAN))[o] = 0.f; return; }
}

// ---------------- k2: RMSNorm -> xn (bf16) ----------------
__global__ __launch_bounds__(128) void k_rmsnorm(const void* x, char* ws){
    const int flag = *(const int*)(ws + O_FLAG);
    const float* lnw = (const float*)(ws + O_LNW);
    ushort_t* xn = (ushort_t*)(ws + O_XN);
    long row = blockIdx.x;
    int tid = threadIdx.x;
    float v[3];
    if (flag){
        const ushort_t* xb = (const ushort_t*)x;
        #pragma unroll
        for (int c = 0; c < 3; c++) v[c] = bf2f(xb[row*384 + tid + c*128]);
    } else {
        const float* xf = (const float*)x;
        #pragma unroll
        for (int c = 0; c < 3; c++) v[c] = xf[row*384 + tid + c*128];
    }
    __shared__ float red[128];
    red[tid] = v[0]*v[0] + v[1]*v[1] + v[2]*v[2];
    __syncthreads();
    for (int st = 64; st > 0; st >>= 1){
        if (tid < st) red[tid] += red[tid + st];
        __syncthreads();
    }
    float scale = rsqrtf(red[0] * (1.f/384.f) + 1e-5f);
    #pragma unroll
    for (int c = 0; c < 3; c++)
        xn[row*384 + tid + c*128] = f2bf(v[c] * scale * lnw[tid + c*128]);
}

// ---------------- k3: xmean[b,d] = mean_L x ----------------
__global__ __launch_bounds__(256) void k_xmean(const void* x, char* ws){
    const int flag = *(const int*)(ws + O_FLAG);
    float* xmean = (float*)(ws + O_XMEAN);
    int b = blockIdx.x, d0 = blockIdx.y*128, l0 = blockIdx.z*256;
    int tid = threadIdx.x, dl = tid & 127, lh = tid >> 7;
    float acc = 0.f;
    if (flag){
        const ushort_t* xb = (const ushort_t*)x;
        for (int l = l0 + lh; l < l0 + 256; l += 2)
            acc += bf2f(xb[((long)b*L_ + l)*384 + d0 + dl]);
    } else {
        const float* xf = (const float*)x;
        for (int l = l0 + lh; l < l0 + 256; l += 2)
            acc += xf[((long)b*L_ + l)*384 + d0 + dl];
    }
    __shared__ float s[256];
    s[tid] = acc; __syncthreads();
    if (tid < 128)
        atomicAdd(&xmean[b*384 + d0 + dl], (s[tid] + s[tid+128]) * (1.f/L_));
}

// ---------------- k4: GEMM1  xn @ W_in -> xp | silu(z) ---------
__global__ __launch_bounds__(256) void k_gemm1(char* ws){
    const ushort_t* xn = (const ushort_t*)(ws + O_XN);
    const ushort_t* wT = (const ushort_t*)(ws + O_WINT);
    ushort_t* xp = (ushort_t*)(ws + O_XP);
    ushort_t* zz = (ushort_t*)(ws + O_Z);
    __shared__ ushort_t sA[128*32];
    __shared__ ushort_t sB[128*32];
    int tid = threadIdx.x, w = tid >> 6, l = tid & 63;
    long m0 = (long)blockIdx.x * 128;
    int n0 = blockIdx.y * 128;
    f32x4 acc[4][4] = {};
    int lr = l >> 2, lk = (l & 3) * 8;
    const ushort_t* gA = xn + (m0 + w*16 + lr)*384 + lk;
    const ushort_t* gB = wT + ((long)(n0 + w*16 + lr))*384 + lk;
    ushort_t* lA = &sA[w*16*32];
    ushort_t* lB = &sB[w*16*32];
    int wm = w & 1, wn = w >> 1;
    int arow = wm*64 + (l & 15);
    int brow = wn*64 + (l & 15);
    int koff = (l >> 4) * 8;
    for (int kc = 0; kc < 12; kc++){
        int k0 = kc * 32;
        gload_lds16(gA + k0,           lA);
        gload_lds16(gA + k0 + 64*384,  lA + 64*32);
        gload_lds16(gB + k0,           lB);
        gload_lds16(gB + k0 + 64*384,  lB + 64*32);
        __syncthreads();
        bf16x8 af[4], bfv[4];
        #pragma unroll
        for (int i = 0; i < 4; i++){
            af[i]  = *(const bf16x8*)&sA[(arow + i*16)*32 + koff];
            bfv[i] = *(const bf16x8*)&sB[(brow + i*16)*32 + koff];
        }
        #pragma unroll
        for (int mb = 0; mb < 4; mb++)
            #pragma unroll
            for (int nb = 0; nb < 4; nb++)
                acc[mb][nb] = __builtin_amdgcn_mfma_f32_16x16x32_bf16(af[mb], bfv[nb], acc[mb][nb], 0, 0, 0);
        __syncthreads();
    }
    ushort_t* outp; int nc0; bool isz;
    if (n0 < 768){ outp = xp; nc0 = n0; isz = false; }
    else { outp = zz; nc0 = n0 - 768; isz = true; }
    int rbase = (l >> 4) * 4, cl = l & 15;
    #pragma unroll
    for (int mb = 0; mb < 4; mb++)
        #pragma unroll
        for (int nb = 0; nb < 4; nb++){
            long row = m0 + wm*64 + mb*16 + rbase;
            int col = nc0 + wn*64 + nb*16 + cl;
            #pragma unroll
            for (int r = 0; r < 4; r++){
                float v = acc[mb][nb][r];
                if (isz) v = v * sigm(v);        // fused silu for z
                outp[(row + r)*768 + col] = f2bf(v);
            }
        }
}

// ---------------- k5: causal depthwise conv K=4 + SiLU ----------------
__global__ __launch_bounds__(256) void k_conv(char* ws){
    const ushort_t* xp = (const ushort_t*)(ws + O_XP);
    ushort_t* xc = (ushort_t*)(ws + O_XC);
    const float* cw = (const float*)(ws + O_CONVW);
    const float* cb = (const float*)(ws + O_CONVB);
    int d = blockIdx.x*256 + threadIdx.x;
    int t0 = blockIdx.y * 8;
    int b = blockIdx.z;
    long rbase = (long)b * L_;
    float w0 = cw[d*4], w1 = cw[d*4+1], w2 = cw[d*4+2], w3 = cw[d*4+3];
    float bias = cb[d];
    float xv[11];
    #pragma unroll
    for (int i = 0; i < 11; i++){
        int t = t0 - 3 + i;
        xv[i] = (t >= 0) ? bf2f(xp[(rbase + t)*768 + d]) : 0.f;
    }
    #pragma unroll
    for (int tt = 0; tt < 8; tt++){
        float v = bias + xv[tt]*w0 + xv[tt+1]*w1 + xv[tt+2]*w2 + xv[tt+3]*w3;
        v = v * sigm(v);
        xc[(rbase + t0 + tt)*768 + d] = f2bf(v);
    }
}

// ---------------- k6: xproj  xc @ W_xproj -> x_dbl[32768,56] ----
__global__ __launch_bounds__(256) void k_xproj(char* ws){
    const ushort_t* xc = (const ushort_t*)(ws + O_XC);
    const ushort_t* wT = (const ushort_t*)(ws + O_WXT);
    float* xdbl = (float*)(ws + O_XDBL);
    __shared__ ushort_t sA[128*32];
    __shared__ ushort_t sB[64*32];
    int tid = threadIdx.x, w = tid >> 6, l = tid & 63;
    long m0 = (long)blockIdx.x * 128;
    f32x4 acc[2][4] = {};
    int lr = l >> 2, lk = (l & 3) * 8;
    const ushort_t* gA = xc + (m0 + w*16 + lr)*768 + lk;
    const ushort_t* gB = wT + ((long)(w*16 + lr))*768 + lk;
    ushort_t* lA = &sA[w*16*32];
    ushort_t* lB = &sB[w*16*32];
    int arow0 = w*32 + (l & 15);
    int brow = l & 15;
    int koff = (l >> 4) * 8;
    for (int kc = 0; kc < 24; kc++){
        int k0 = kc * 32;
        gload_lds16(gA + k0,           lA);
        gload_lds16(gA + k0 + 64*768,  lA + 64*32);
        gload_lds16(gB + k0,           lB);
        __syncthreads();
        bf16x8 af[2], bfv[4];
        af[0] = *(const bf16x8*)&sA[arow0*32 + koff];
        af[1] = *(const bf16x8*)&sA[(arow0+16)*32 + koff];
        #pragma unroll
        for (int nb = 0; nb < 4; nb++)
            bfv[nb] = *(const bf16x8*)&sB[(nb*16 + brow)*32 + koff];
        #pragma unroll
        for (int mb = 0; mb < 2; mb++)
            #pragma unroll
            for (int nb = 0; nb < 4; nb++)
                acc[mb][nb] = __builtin_amdgcn_mfma_f32_16x16x32_bf16(af[mb], bfv[nb], acc[mb][nb], 0, 0, 0);
        __syncthreads();
    }
    int rbase = (l >> 4) * 4, cl = l & 15;
    #pragma unroll
    for (int mb = 0; mb < 2; mb++)
        #pragma unroll
        for (int nb = 0; nb < 4; nb++){
            int col = nb*16 + cl;
            if (col < 56){
                long row = m0 + w*32 + mb*16 + rbase;
                #pragma unroll
                for (int r = 0; r < 4; r++)
                    xdbl[(row + r)*56 + col] = acc[mb][nb][r];
            }
        }
}

// ---------------- k7: chunk-parallel selective scan (pass 1) --------------
// v9. R4 post-mortem: v8 decisively split the two theories. (a) CONFIRMED:
// LDS granule rounding — 24192 request allocated as 24576, and occupancy
// jumped 40->68.7% (6 blocks/CU resident). (b) ALSO REAL but toxic:
// launch_bounds min-waves=6 makes the allocator spill the loop state
// (VGPR 40, WRITE_SIZE 39MB->3.2GB scratch, VALUBusy 6%, 1504us) — same
// signature as v6, which also used min-waves=6. Empirical rule: this body
// compiles clean only at min-waves<=5 (VGPR 44-48, v4/v7).
// v9 = v7's exact codegen environment (256 thr, bounds(256,5)) with the
// ONLY change being STG 112->108 so the LDS allocation lands at 24576 and
// the hardware can fit 6 blocks/CU. Decisive: if occ ~69% -> ~115us; if
// occ stays 40% the (256,5) bound itself caps residency (next: no bounds).
__global__ __launch_bounds__(256, 5) void k_scan(char* ws){
    const ushort_t* xc = (const ushort_t*)(ws + O_XC);
    const ushort_t* wz = (const ushort_t*)(ws + O_Z);      // silu(z)
    const float* xdbl = (const float*)(ws + O_XDBL);
    const float* Ag = (const float*)(ws + O_A);            // -exp(A_log)*log2e
    const float* Dsk = (const float*)(ws + O_DSKIP);
    const float* Wdt = (const float*)(ws + O_WDT);
    const float* dtb = (const float*)(ws + O_DTB);
    float* FX = (float*)(ws + O_FX);
    int tid = threadIdx.x;
    int half = tid & 1, p = tid >> 1;          // 128 d per block, pair = lanes 2k,2k+1
    int d = blockIdx.x * 128 + p;
    int c = blockIdx.y, b = blockIdx.z;
    long row0 = (long)b * L_ + (long)c * CL;

    __shared__ float sXD[STG*56];              // 24192 B req -> 24576 alloc
    const float* xdg = xdbl + row0*56;         // global source (tail rows read direct)
    {
        const f32x4* src = (const f32x4*)xdg;  // 1512 vec4 staged
        f32x4* dst = (f32x4*)sXD;
        #pragma unroll
        for (int i = 0; i < 5; i++) dst[tid + i*256] = src[tid + i*256];
        if (tid < 232) dst[tid + 1280] = src[tid + 1280];
    }

    f32x2 wdt2[6];
    #pragma unroll
    for (int k = 0; k < 6; k++){
        wdt2[k][0] = Wdt[(half*12 + 2*k    )*768 + d];
        wdt2[k][1] = Wdt[(half*12 + 2*k + 1)*768 + d];
    }
    float dbias = half ? 0.f : dtb[d];
    f32x2 Av2[4];
    #pragma unroll
    for (int j = 0; j < 4; j++){
        Av2[j][0] = Ag[d*16 + half*8 + 2*j];
        Av2[j][1] = Ag[d*16 + half*8 + 2*j + 1];
    }
    float Dv = Dsk[d];
    __syncthreads();                           // the only barrier

    f32x2 h2[4], q2[4], G2[4];
    #pragma unroll
    for (int j = 0; j < 4; j++){
        h2[j] = f32x2{0.f, 0.f}; G2[j] = f32x2{0.f, 0.f}; q2[j] = f32x2{1.f, 1.f};
    }
    f32x2 ysum2 = {0.f, 0.f};
    float sdw = 0.f;

    const ushort_t* gx = (half ? wz : xc) + row0*768 + d;   // parity-split stream

#define SCAN_STEP                                                           \
    {                                                                       \
        ushort_t mine = gx[t*768];                                          \
        f32x2 acc2 = {dbias, 0.f};                                          \
        _Pragma("unroll")                                                   \
        for (int j = 0; j < 3; j++){                                        \
            f32x4 v = *(const f32x4*)&xd[half*12 + j*4];                    \
            acc2 += f32x2{v[0], v[1]} * wdt2[2*j];                          \
            acc2 += f32x2{v[2], v[3]} * wdt2[2*j + 1];                      \
        }                                                                   \
        float dt_p = acc2[0] + acc2[1];                                     \
        float dtv = dt_p + __shfl_xor(dt_p, 1);                             \
        float e = __builtin_amdgcn_exp2f(dtv * 1.4426950408889634f);        \
        float sp = 0.69314718055994531f * __builtin_amdgcn_logf(1.f + e);   \
        dtv = (dtv > 20.f) ? dtv : sp;                                      \
        u32 other = (u32)__shfl_xor((int)(u32)mine, 1);                     \
        float xcv = bf2f(half ? (ushort_t)other : mine);                    \
        float wzv = bf2f(half ? mine : (ushort_t)other);                    \
        float u = dtv * xcv;                                                \
        f32x2 u2 = {u, u}, wz2 = {wzv, wzv}, dtv2 = {dtv, dtv};             \
        f32x4 Bva = *(const f32x4*)&xd[24 + half*8];                        \
        f32x4 Bvb = *(const f32x4*)&xd[28 + half*8];                        \
        f32x4 Cva = *(const f32x4*)&xd[40 + half*8];                        \
        f32x4 Cvb = *(const f32x4*)&xd[44 + half*8];                        \
        _Pragma("unroll")                                                   \
        for (int j = 0; j < 4; j++){                                        \
            f32x2 Bj = (j < 2) ? f32x2{Bva[2*j], Bva[2*j+1]} : f32x2{Bvb[2*j-4], Bvb[2*j-3]}; \
            f32x2 Cj = (j < 2) ? f32x2{Cva[2*j], Cva[2*j+1]} : f32x2{Cvb[2*j-4], Cvb[2*j-3]}; \
            f32x2 arg = dtv2 * Av2[j];                                      \
            f32x2 dA;                                                       \
            dA[0] = __builtin_amdgcn_exp2f(arg[0]);                         \
            dA[1] = __builtin_amdgcn_exp2f(arg[1]);                         \
            h2[j] = dA * h2[j] + u2 * Bj;                                   \
            f32x2 Cw = Cj * wz2;                                            \
            ysum2 += h2[j] * Cw;                                            \
            q2[j] = q2[j] * dA;                                             \
            G2[j] += q2[j] * Cw;                                            \
        }                                                                   \
        sdw += xcv * wzv;                                                   \
    }

    #pragma unroll 8
    for (int t = 0; t < STG; t++){
        const float* xd = &sXD[t*56];          // LDS-staged rows
        SCAN_STEP
    }
    #pragma unroll 8
    for (int t = STG; t < CL; t++){
        const float* xd = xdg + t*56;          // tail rows direct from global
        SCAN_STEP
    }
#undef SCAN_STEP

    float ys = ysum2[0] + ysum2[1] + (half ? 0.f : Dv * sdw);
    ys += __shfl_xor(ys, 1);
    long fb = ((long)(b*NCHUNK + c)*49)*768 + d;
    if (!half) FX[fb] = ys;
    #pragma unroll
    for (int j = 0; j < 4; j++){
        int sg = half*8 + 2*j;
        FX[fb + (1+sg)*768]  = h2[j][0];  FX[fb + (2+sg)*768]  = h2[j][1];
        FX[fb + (17+sg)*768] = q2[j][0];  FX[fb + (18+sg)*768] = q2[j][1];
        FX[fb + (33+sg)*768] = G2[j][0];  FX[fb + (34+sg)*768] = G2[j][1];
    }
}

// ---------------- k8: scan pass 2 — stitch chunks (thread per (b,d,s)) ----
__global__ __launch_bounds__(256) void k_fix(char* ws){
    const float* FX = (const float*)(ws + O_FX);
    float* ymean = (float*)(ws + O_YMEAN);
    int tid = threadIdx.x;
    int dl = tid & 15, s = tid >> 4;
    int d = blockIdx.x * 16 + dl;
    int b = blockIdx.y;
    float Hrun = 0.f, ys = 0.f;
    for (int c = 0; c < NCHUNK; c++){
        long fb = ((long)(b*NCHUNK + c)*49)*768 + d;
        float Gs = FX[fb + (33+s)*768];
        float Hs = FX[fb + (1+s)*768];
        float qs = FX[fb + (17+s)*768];
        ys += Hrun * Gs;
        if (s == 0) ys += FX[fb];
        Hrun = Hs + qs * Hrun;
    }
    __shared__ float sR[256];
    sR[tid] = ys;
    __syncthreads();
    #pragma unroll
    for (int st = 8; st >= 1; st >>= 1){
        if (s < st) sR[tid] += sR[tid + st*16];
        __syncthreads();
    }
    if (s == 0) ymean[b*768 + d] = sR[dl] * (1.f/L_);
}

// ---------------- k9: head part 1: pooled -> h = pooled@W_fc + b_fc ------
__global__ __launch_bounds__(256) void k_head1(char* ws){
    const float* ymean = (const float*)(ws + O_YMEAN);
    const float* xmean = (const float*)(ws + O_XMEAN);
    const float* Wout = (const float*)(ws + O_WOUT);
    const float* Wfc = (const float*)(ws + O_WFC);
    const float* bfc = (const float*)(ws + O_BFC);
    float* hbuf = (float*)(ws + O_H);
    int b = blockIdx.x, tid = threadIdx.x;
    __shared__ float sY[768];
    __shared__ float sP[384];
    sY[tid] = ymean[b*768 + tid];
    sY[tid+256] = ymean[b*768 + tid + 256];
    sY[tid+512] = ymean[b*768 + tid + 512];
    __syncthreads();
    for (int d = tid; d < 384; d += 256){
        float v = xmean[b*384 + d];
        for (int i = 0; i < 768; i++) v += sY[i] * Wout[i*384 + d];
        sP[d] = v;
    }
    __syncthreads();
    float v = bfc[tid];
    for (int dd = 0; dd < 384; dd++) v += sP[dd] * Wfc[dd*256 + tid];
    hbuf[b*256 + tid] = v;
}

// ---------------- k10: head part 2: batchnorm + relu + classifier --------
__global__ __launch_bounds__(384) void k_head2(char* ws, void* out){
    const int flag = *(const int*)(ws + O_FLAG);
    const float* hbuf = (const float*)(ws + O_H);
    const float* gam = (const float*)(ws + O_GAM);
    const float* bet = (const float*)(ws + O_BET);
    const float* Wcls = (const float*)(ws + O_WCLS);
    const float* bcls = (const float*)(ws + O_BCLS);
    int tid = threadIdx.x;
    __shared__ float sH[8*256];
    if (tid < 256){
        float hv[8]; float mu = 0.f;
        #pragma unroll
        for (int b = 0; b < 8; b++){ hv[b] = hbuf[b*256 + tid]; mu += hv[b]; }
        mu *= 0.125f;
        float var = 0.f;
        #pragma unroll
        for (int b = 0; b < 8; b++){ float dv = hv[b]-mu; var += dv*dv; }
        var *= 0.125f;
        float rs = rsqrtf(var + 1e-5f);
        #pragma unroll
        for (int b = 0; b < 8; b++){
            float t = (hv[b]-mu)*rs*gam[tid] + bet[tid];
            sH[b*256 + tid] = t > 0.f ? t : 0.f;
        }
    }
    __syncthreads();
    if (tid < 320){
        int b = tid / 40, c = tid % 40;
        float acc = bcls[c];
        for (int j = 0; j < 256; j++) acc += sH[b*256 + j] * Wcls[j*40 + c];
        if (flag) ((ushort_t*)out)[b*40 + c] = f2bf(acc);
        else      ((float*)out)[b*40 + c] = acc;
    }
}

// ---------------- launch ----------------
extern "C" void kernel_launch(void* const* d_in, const int* in_sizes, int n_in,
                              void* d_out, int out_size, void* d_ws, size_t ws_size,
                              hipStream_t stream){
    (void)in_sizes; (void)n_in; (void)out_size; (void)ws_size;
    char* ws = (char*)d_ws;
    Ptrs ps;
    for (int i = 0; i < 17; i++) ps.p[i] = d_in[i];

    k_detect<<<1, 256, 0, stream>>>(d_in[0], ws);
    k_prep<<<(unsigned)((N_PREP + 255) / 256), 256, 0, stream>>>(ps, ws);
    k_rmsnorm<<<ML_, 128, 0, stream>>>(d_in[0], ws);
    k_xmean<<<dim3(8, 3, 16), 256, 0, stream>>>(d_in[0], ws);
    k_gemm1<<<dim3(ML_/128, 12), 256, 0, stream>>>(ws);
    k_conv<<<dim3(3, L_/8, B_), 256, 0, stream>>>(ws);
    k_xproj<<<ML_/128, 256, 0, stream>>>(ws);
    k_scan<<<dim3(6, NCHUNK, B_), 256, 0, stream>>>(ws);
    k_fix<<<dim3(48, B_), 256, 0, stream>>>(ws);
    k_head1<<<B_, 256, 0, stream>>>(ws);
    k_head2<<<1, 384, 0, stream>>>(ws, d_out);
}

// Round 6
// 508.845 us; speedup vs baseline: 4.4098x; 4.4098x over previous
//
#include <hip/hip_runtime.h>

typedef unsigned short ushort_t;
typedef unsigned int u32;
typedef float f32x4 __attribute__((ext_vector_type(4)));
typedef float f32x2 __attribute__((ext_vector_type(2)));
typedef __bf16 bf16x8 __attribute__((ext_vector_type(8)));

#define B_ 8
#define L_ 4096
#define D_ 384
#define DI_ 768
#define S_ 16
#define NC_ 40
#define ML_ (B_*L_)   // 32768 rows
#define NCHUNK 32
#define CL 128        // chunk length (L_/NCHUNK)

// ---------------- workspace layout (bytes) ----------------
// ~154 MB total. Aliasing:
//   XN lives in XC region (dead after gemm1, before conv writes XC);
//   XDBL lives at start of XP region (XP dead after conv);
//   FX (chunk summaries, 38.5 MB) lives in XP region after XDBL.
constexpr size_t au(size_t x){ return (x + 255) & ~size_t(255); }
constexpr size_t O_FLAG = 0;                                   // int
constexpr size_t O_LNW  = 256;                                 // 384 f32
constexpr size_t O_CONVW= au(O_LNW  + 384*4);                  // 3072 f32
constexpr size_t O_CONVB= au(O_CONVW+ 3072*4);                 // 768 f32
constexpr size_t O_WDT  = au(O_CONVB+ 768*4);                  // 18432 f32
constexpr size_t O_DTB  = au(O_WDT  + 18432*4);                // 768 f32
constexpr size_t O_A    = au(O_DTB  + 768*4);                  // 12288 f32 (A = -exp(A_log)*log2e)
constexpr size_t O_DSKIP= au(O_A    + 12288*4);                // 768 f32
constexpr size_t O_WOUT = au(O_DSKIP+ 768*4);                  // 294912 f32
constexpr size_t O_WFC  = au(O_WOUT + 294912*4);               // 98304 f32
constexpr size_t O_BFC  = au(O_WFC  + 98304*4);                // 256 f32
constexpr size_t O_GAM  = au(O_BFC  + 256*4);
constexpr size_t O_BET  = au(O_GAM  + 256*4);
constexpr size_t O_WCLS = au(O_BET  + 256*4);                  // 10240 f32
constexpr size_t O_BCLS = au(O_WCLS + 10240*4);                // 40 f32
constexpr size_t O_XMEAN= au(O_BCLS + 40*4);                   // 8*384 f32 (atomic acc, zeroed in prep)
constexpr size_t O_YMEAN= au(O_XMEAN+ 3072*4);                 // 8*768 f32
constexpr size_t O_H    = au(O_YMEAN+ 6144*4);                 // 8*256 f32
constexpr size_t O_WINT = au(O_H    + 2048*4);                 // W_in^T  [1536][384] bf16
constexpr size_t O_WXT  = au(O_WINT + (size_t)589824*2);       // W_xproj^T padded [64][768] bf16
constexpr size_t O_XP   = au(O_WXT  + (size_t)49152*2);        // [32768][768] bf16
constexpr size_t O_XDBL = O_XP;                                // alias: [32768][56] f32 (after conv)
constexpr size_t O_FX   = au(O_XDBL + (size_t)ML_*56*4);       // [b][c][49][768] f32 chunk summaries
constexpr size_t FX_SZ  = (size_t)B_*NCHUNK*49*768*4;          // 38.5 MB
constexpr size_t O_Z    = au(O_XP   + (size_t)ML_*768*2);      // [32768][768] bf16 (holds silu(z))
constexpr size_t O_XCU  = au(O_Z    + (size_t)ML_*768*2);      // union region, 50.3 MB
constexpr size_t O_XN   = O_XCU;                               // [32768][384] bf16 (dead after gemm1)
constexpr size_t O_XC   = O_XCU;                               // [32768][768] bf16
constexpr size_t WS_NEED= O_XCU + (size_t)ML_*768*2;           // ~154 MB
static_assert(O_FX + FX_SZ <= O_Z, "FX must fit in dead XP tail");

// ---------------- helpers ----------------
__device__ inline float bf2f(ushort_t u){ return __uint_as_float(((u32)u) << 16); }
__device__ inline ushort_t f2bf(float f){
    u32 x = __float_as_uint(f);
    u32 r = (x + 0x7fffu + ((x >> 16) & 1u)) >> 16;   // RNE
    return (ushort_t)r;
}
__device__ inline float ldf(const void* p, long i, int flag){
    return flag ? bf2f(((const ushort_t*)p)[i]) : ((const float*)p)[i];
}
__device__ inline ushort_t ldbf(const void* p, long i, int flag){
    return flag ? ((const ushort_t*)p)[i] : f2bf(((const float*)p)[i]);
}
__device__ inline float sigm(float v){ return 1.f / (1.f + __expf(-v)); }

__device__ inline void gload_lds16(const void* g, void* l){
    __builtin_amdgcn_global_load_lds(
        (const __attribute__((address_space(1))) u32*)g,
        (__attribute__((address_space(3))) u32*)l, 16, 0, 0);
}

struct Ptrs { const void* p[17]; };

// ---------------- k0: dtype detect ----------------
__global__ void k_detect(const void* x, char* ws){
    __shared__ float s[256];
    int tid = threadIdx.x;
    s[tid] = fabsf(bf2f(((const ushort_t*)x)[tid]));
    __syncthreads();
    for (int st = 128; st > 0; st >>= 1){
        if (tid < st) s[tid] = fmaxf(s[tid], s[tid + st]);
        __syncthreads();
    }
    if (tid == 0) *(int*)(ws + O_FLAG) = (s[0] < 1e4f) ? 1 : 0;
}

// ---------------- k1: weight prep ----------------
#define N_PREP 1082792L
__global__ __launch_bounds__(256) void k_prep(Ptrs ps, char* ws){
    const int flag = *(const int*)(ws + O_FLAG);
    long o = (long)blockIdx.x * 256 + threadIdx.x;
    if (o < 384){ ((float*)(ws+O_LNW))[o]  = ldf(ps.p[1],o,flag); return; }  o -= 384;
    if (o < 3072){ ((float*)(ws+O_CONVW))[o]= ldf(ps.p[3],o,flag); return; } o -= 3072;
    if (o < 768){ ((float*)(ws+O_CONVB))[o]= ldf(ps.p[4],o,flag); return; }  o -= 768;
    if (o < 18432){ ((float*)(ws+O_WDT))[o]= ldf(ps.p[6],o,flag); return; }  o -= 18432;
    if (o < 768){ ((float*)(ws+O_DTB))[o]  = ldf(ps.p[7],o,flag); return; }  o -= 768;
    if (o < 768){ ((float*)(ws+O_DSKIP))[o]= ldf(ps.p[9],o,flag); return; }  o -= 768;
    if (o < 294912){ ((float*)(ws+O_WOUT))[o]= ldf(ps.p[10],o,flag); return; } o -= 294912;
    if (o < 98304){ ((float*)(ws+O_WFC))[o]= ldf(ps.p[11],o,flag); return; } o -= 98304;
    if (o < 256){ ((float*)(ws+O_BFC))[o]  = ldf(ps.p[12],o,flag); return; } o -= 256;
    if (o < 256){ ((float*)(ws+O_GAM))[o]  = ldf(ps.p[13],o,flag); return; } o -= 256;
    if (o < 256){ ((float*)(ws+O_BET))[o]  = ldf(ps.p[14],o,flag); return; } o -= 256;
    if (o < 10240){ ((float*)(ws+O_WCLS))[o]= ldf(ps.p[15],o,flag); return; } o -= 10240;
    if (o < 40){ ((float*)(ws+O_BCLS))[o]  = ldf(ps.p[16],o,flag); return; } o -= 40;
    // A = -exp(A_log) * log2(e)   (scan uses exp2)
    if (o < 12288){ ((float*)(ws+O_A))[o]  = -__expf(ldf(ps.p[8],o,flag)) * 1.4426950408889634f; return; } o -= 12288;
    if (o < 589824){                     // W_in [384,1536] -> WinT [1536][384]
        long n = o / 384, k = o % 384;
        ((ushort_t*)(ws+O_WINT))[o] = ldbf(ps.p[2], k*1536 + n, flag); return;
    } o -= 589824;
    if (o < 49152){                      // W_xproj [768,56] -> WxT [64][768], zero-pad n>=56
        long n = o / 768, k = o % 768;
        ((ushort_t*)(ws+O_WXT))[o] = (n < 56) ? ldbf(ps.p[5], k*56 + n, flag) : (ushort_t)0;
        return;
    } o -= 49152;
    if (o < 3072){ ((float*)(ws+O_XMEAN))[o] = 0.f; return; }
}

// ---------------- k2: RMSNorm -> xn (bf16) ----------------
__global__ __launch_bounds__(128) void k_rmsnorm(const void* x, char* ws){
    const int flag = *(const int*)(ws + O_FLAG);
    const float* lnw = (const float*)(ws + O_LNW);
    ushort_t* xn = (ushort_t*)(ws + O_XN);
    long row = blockIdx.x;
    int tid = threadIdx.x;
    float v[3];
    if (flag){
        const ushort_t* xb = (const ushort_t*)x;
        #pragma unroll
        for (int c = 0; c < 3; c++) v[c] = bf2f(xb[row*384 + tid + c*128]);
    } else {
        const float* xf = (const float*)x;
        #pragma unroll
        for (int c = 0; c < 3; c++) v[c] = xf[row*384 + tid + c*128];
    }
    __shared__ float red[128];
    red[tid] = v[0]*v[0] + v[1]*v[1] + v[2]*v[2];
    __syncthreads();
    for (int st = 64; st > 0; st >>= 1){
        if (tid < st) red[tid] += red[tid + st];
        __syncthreads();
    }
    float scale = rsqrtf(red[0] * (1.f/384.f) + 1e-5f);
    #pragma unroll
    for (int c = 0; c < 3; c++)
        xn[row*384 + tid + c*128] = f2bf(v[c] * scale * lnw[tid + c*128]);
}

// ---------------- k3: xmean[b,d] = mean_L x ----------------
__global__ __launch_bounds__(256) void k_xmean(const void* x, char* ws){
    const int flag = *(const int*)(ws + O_FLAG);
    float* xmean = (float*)(ws + O_XMEAN);
    int b = blockIdx.x, d0 = blockIdx.y*128, l0 = blockIdx.z*256;
    int tid = threadIdx.x, dl = tid & 127, lh = tid >> 7;
    float acc = 0.f;
    if (flag){
        const ushort_t* xb = (const ushort_t*)x;
        for (int l = l0 + lh; l < l0 + 256; l += 2)
            acc += bf2f(xb[((long)b*L_ + l)*384 + d0 + dl]);
    } else {
        const float* xf = (const float*)x;
        for (int l = l0 + lh; l < l0 + 256; l += 2)
            acc += xf[((long)b*L_ + l)*384 + d0 + dl];
    }
    __shared__ float s[256];
    s[tid] = acc; __syncthreads();
    if (tid < 128)
        atomicAdd(&xmean[b*384 + d0 + dl], (s[tid] + s[tid+128]) * (1.f/L_));
}

// ---------------- k4: GEMM1  xn @ W_in -> xp | silu(z) ---------
__global__ __launch_bounds__(256) void k_gemm1(char* ws){
    const ushort_t* xn = (const ushort_t*)(ws + O_XN);
    const ushort_t* wT = (const ushort_t*)(ws + O_WINT);
    ushort_t* xp = (ushort_t*)(ws + O_XP);
    ushort_t* zz = (ushort_t*)(ws + O_Z);
    __shared__ ushort_t sA[128*32];
    __shared__ ushort_t sB[128*32];
    int tid = threadIdx.x, w = tid >> 6, l = tid & 63;
    long m0 = (long)blockIdx.x * 128;
    int n0 = blockIdx.y * 128;
    f32x4 acc[4][4] = {};
    int lr = l >> 2, lk = (l & 3) * 8;
    const ushort_t* gA = xn + (m0 + w*16 + lr)*384 + lk;
    const ushort_t* gB = wT + ((long)(n0 + w*16 + lr))*384 + lk;
    ushort_t* lA = &sA[w*16*32];
    ushort_t* lB = &sB[w*16*32];
    int wm = w & 1, wn = w >> 1;
    int arow = wm*64 + (l & 15);
    int brow = wn*64 + (l & 15);
    int koff = (l >> 4) * 8;
    for (int kc = 0; kc < 12; kc++){
        int k0 = kc * 32;
        gload_lds16(gA + k0,           lA);
        gload_lds16(gA + k0 + 64*384,  lA + 64*32);
        gload_lds16(gB + k0,           lB);
        gload_lds16(gB + k0 + 64*384,  lB + 64*32);
        __syncthreads();
        bf16x8 af[4], bfv[4];
        #pragma unroll
        for (int i = 0; i < 4; i++){
            af[i]  = *(const bf16x8*)&sA[(arow + i*16)*32 + koff];
            bfv[i] = *(const bf16x8*)&sB[(brow + i*16)*32 + koff];
        }
        #pragma unroll
        for (int mb = 0; mb < 4; mb++)
            #pragma unroll
            for (int nb = 0; nb < 4; nb++)
                acc[mb][nb] = __builtin_amdgcn_mfma_f32_16x16x32_bf16(af[mb], bfv[nb], acc[mb][nb], 0, 0, 0);
        __syncthreads();
    }
    ushort_t* outp; int nc0; bool isz;
    if (n0 < 768){ outp = xp; nc0 = n0; isz = false; }
    else { outp = zz; nc0 = n0 - 768; isz = true; }
    int rbase = (l >> 4) * 4, cl = l & 15;
    #pragma unroll
    for (int mb = 0; mb < 4; mb++)
        #pragma unroll
        for (int nb = 0; nb < 4; nb++){
            long row = m0 + wm*64 + mb*16 + rbase;
            int col = nc0 + wn*64 + nb*16 + cl;
            #pragma unroll
            for (int r = 0; r < 4; r++){
                float v = acc[mb][nb][r];
                if (isz) v = v * sigm(v);        // fused silu for z
                outp[(row + r)*768 + col] = f2bf(v);
            }
        }
}

// ---------------- k5: causal depthwise conv K=4 + SiLU ----------------
__global__ __launch_bounds__(256) void k_conv(char* ws){
    const ushort_t* xp = (const ushort_t*)(ws + O_XP);
    ushort_t* xc = (ushort_t*)(ws + O_XC);
    const float* cw = (const float*)(ws + O_CONVW);
    const float* cb = (const float*)(ws + O_CONVB);
    int d = blockIdx.x*256 + threadIdx.x;
    int t0 = blockIdx.y * 8;
    int b = blockIdx.z;
    long rbase = (long)b * L_;
    float w0 = cw[d*4], w1 = cw[d*4+1], w2 = cw[d*4+2], w3 = cw[d*4+3];
    float bias = cb[d];
    float xv[11];
    #pragma unroll
    for (int i = 0; i < 11; i++){
        int t = t0 - 3 + i;
        xv[i] = (t >= 0) ? bf2f(xp[(rbase + t)*768 + d]) : 0.f;
    }
    #pragma unroll
    for (int tt = 0; tt < 8; tt++){
        float v = bias + xv[tt]*w0 + xv[tt+1]*w1 + xv[tt+2]*w2 + xv[tt+3]*w3;
        v = v * sigm(v);
        xc[(rbase + t0 + tt)*768 + d] = f2bf(v);
    }
}

// ---------------- k6: xproj  xc @ W_xproj -> x_dbl[32768,56] ----
__global__ __launch_bounds__(256) void k_xproj(char* ws){
    const ushort_t* xc = (const ushort_t*)(ws + O_XC);
    const ushort_t* wT = (const ushort_t*)(ws + O_WXT);
    float* xdbl = (float*)(ws + O_XDBL);
    __shared__ ushort_t sA[128*32];
    __shared__ ushort_t sB[64*32];
    int tid = threadIdx.x, w = tid >> 6, l = tid & 63;
    long m0 = (long)blockIdx.x * 128;
    f32x4 acc[2][4] = {};
    int lr = l >> 2, lk = (l & 3) * 8;
    const ushort_t* gA = xc + (m0 + w*16 + lr)*768 + lk;
    const ushort_t* gB = wT + ((long)(w*16 + lr))*768 + lk;
    ushort_t* lA = &sA[w*16*32];
    ushort_t* lB = &sB[w*16*32];
    int arow0 = w*32 + (l & 15);
    int brow = l & 15;
    int koff = (l >> 4) * 8;
    for (int kc = 0; kc < 24; kc++){
        int k0 = kc * 32;
        gload_lds16(gA + k0,           lA);
        gload_lds16(gA + k0 + 64*768,  lA + 64*32);
        gload_lds16(gB + k0,           lB);
        __syncthreads();
        bf16x8 af[2], bfv[4];
        af[0] = *(const bf16x8*)&sA[arow0*32 + koff];
        af[1] = *(const bf16x8*)&sA[(arow0+16)*32 + koff];
        #pragma unroll
        for (int nb = 0; nb < 4; nb++)
            bfv[nb] = *(const bf16x8*)&sB[(nb*16 + brow)*32 + koff];
        #pragma unroll
        for (int mb = 0; mb < 2; mb++)
            #pragma unroll
            for (int nb = 0; nb < 4; nb++)
                acc[mb][nb] = __builtin_amdgcn_mfma_f32_16x16x32_bf16(af[mb], bfv[nb], acc[mb][nb], 0, 0, 0);
        __syncthreads();
    }
    int rbase = (l >> 4) * 4, cl = l & 15;
    #pragma unroll
    for (int mb = 0; mb < 2; mb++)
        #pragma unroll
        for (int nb = 0; nb < 4; nb++){
            int col = nb*16 + cl;
            if (col < 56){
                long row = m0 + w*32 + mb*16 + rbase;
                #pragma unroll
                for (int r = 0; r < 4; r++)
                    xdbl[(row + r)*56 + col] = acc[mb][nb][r];
            }
        }
}

// ---------------- k7: chunk-parallel selective scan (pass 1) --------------
// v10. R5 post-mortem: v9 (STG=108, bounds(256,5), VGPR 48 == healthy v7)
// exploded exactly like v8 (FETCH 1.6GB / WRITE 3.1GB, ~80x algorithmic) ->
// the catastrophe correlates with STG=108/LDS-24576 itself, NOT with launch
// bounds; mechanism unexplained. Also v7's LDS_Block_Size=25088 (not
// rounded) disproves the 4KB-granule theory; 6x25088 already fit, yet v7
// ran 5 blocks/CU. Conclusion: block-residency cannot be raised safely.
// v10 raises PER-WAVE ILP instead: each thread handles TWO d-channels
// (d, d+128), block covers 256 d -> grid 3x32x8 = 768 blocks = 3/CU,
// BELOW every cap ever measured -> one round by construction, no tail.
// xdbl B/C loads + staging shared between channels (loads/step unchanged,
// VALU/step ~1.9x); doubled independent FMA chains raise issue rate.
// Known-good ingredients only: 256 thr, full 128-row stage (28672 B),
// single barrier, parity split. bounds(256,3): 170-VGPR headroom (state
// ~100), max distance from the spill cliff. unroll 4 bounds temporaries.
__global__ __launch_bounds__(256, 3) void k_scan(char* ws){
    const ushort_t* xc = (const ushort_t*)(ws + O_XC);
    const ushort_t* wz = (const ushort_t*)(ws + O_Z);      // silu(z)
    const float* xdbl = (const float*)(ws + O_XDBL);
    const float* Ag = (const float*)(ws + O_A);            // -exp(A_log)*log2e
    const float* Dsk = (const float*)(ws + O_DSKIP);
    const float* Wdt = (const float*)(ws + O_WDT);
    const float* dtb = (const float*)(ws + O_DTB);
    float* FX = (float*)(ws + O_FX);
    int tid = threadIdx.x;
    int half = tid & 1, p = tid >> 1;          // pair = lanes 2k,2k+1; 128 pairs
    int d = blockIdx.x * 256 + p;              // channel A; channel B = d+128
    int c = blockIdx.y, b = blockIdx.z;
    long row0 = (long)b * L_ + (long)c * CL;

    __shared__ float sXD[CL*56];               // 28 KB: whole chunk's xdbl (v4 staging)
    {
        const f32x4* src = (const f32x4*)(xdbl + row0*56);   // 1792 vec4
        f32x4* dst = (f32x4*)sXD;
        #pragma unroll
        for (int i = 0; i < 7; i++) dst[tid + i*256] = src[tid + i*256];
    }

    f32x2 wdtA[6], wdtB[6];
    #pragma unroll
    for (int k = 0; k < 6; k++){
        wdtA[k][0] = Wdt[(half*12 + 2*k    )*768 + d];
        wdtA[k][1] = Wdt[(half*12 + 2*k + 1)*768 + d];
        wdtB[k][0] = Wdt[(half*12 + 2*k    )*768 + d + 128];
        wdtB[k][1] = Wdt[(half*12 + 2*k + 1)*768 + d + 128];
    }
    float dbiasA = half ? 0.f : dtb[d];
    float dbiasB = half ? 0.f : dtb[d + 128];
    f32x2 AvA[4], AvB[4];
    #pragma unroll
    for (int j = 0; j < 4; j++){
        AvA[j][0] = Ag[d*16 + half*8 + 2*j];
        AvA[j][1] = Ag[d*16 + half*8 + 2*j + 1];
        AvB[j][0] = Ag[(d+128)*16 + half*8 + 2*j];
        AvB[j][1] = Ag[(d+128)*16 + half*8 + 2*j + 1];
    }
    float DvA = Dsk[d], DvB = Dsk[d + 128];
    __syncthreads();                           // the only barrier

    f32x2 hA[4], qA[4], GA[4], hB[4], qB[4], GB[4];
    #pragma unroll
    for (int j = 0; j < 4; j++){
        hA[j] = f32x2{0.f,0.f}; GA[j] = f32x2{0.f,0.f}; qA[j] = f32x2{1.f,1.f};
        hB[j] = f32x2{0.f,0.f}; GB[j] = f32x2{0.f,0.f}; qB[j] = f32x2{1.f,1.f};
    }
    f32x2 ysA2 = {0.f,0.f}, ysB2 = {0.f,0.f};
    float sdwA = 0.f, sdwB = 0.f;

    const ushort_t* gx = (half ? wz : xc) + row0*768 + d;   // parity-split stream

    #pragma unroll 4
    for (int t = 0; t < CL; t++){
        ushort_t mA = gx[t*768];
        ushort_t mB = gx[t*768 + 128];
        const float* xd = &sXD[t*56];
        // dt dot for both channels — xd vec4 loads shared
        f32x2 accA = {dbiasA, 0.f}, accB = {dbiasB, 0.f};
        #pragma unroll
        for (int j = 0; j < 3; j++){
            f32x4 v = *(const f32x4*)&xd[half*12 + j*4];
            f32x2 vlo = {v[0], v[1]}, vhi = {v[2], v[3]};
            accA += vlo * wdtA[2*j];  accA += vhi * wdtA[2*j + 1];
            accB += vlo * wdtB[2*j];  accB += vhi * wdtB[2*j + 1];
        }
        float dpA = accA[0] + accA[1], dpB = accB[0] + accB[1];
        float dtA = dpA + __shfl_xor(dpA, 1);
        float dtB = dpB + __shfl_xor(dpB, 1);
        // softplus both
        float eA = __builtin_amdgcn_exp2f(dtA * 1.4426950408889634f);
        float sA_ = 0.69314718055994531f * __builtin_amdgcn_logf(1.f + eA);
        dtA = (dtA > 20.f) ? dtA : sA_;
        float eB = __builtin_amdgcn_exp2f(dtB * 1.4426950408889634f);
        float sB_ = 0.69314718055994531f * __builtin_amdgcn_logf(1.f + eB);
        dtB = (dtB > 20.f) ? dtB : sB_;
        // packed xc/z exchange for both channels in ONE shuffle
        u32 pk = (u32)mA | ((u32)mB << 16);
        u32 other = (u32)__shfl_xor((int)pk, 1);
        ushort_t oA = (ushort_t)(other & 0xffffu), oB = (ushort_t)(other >> 16);
        float xcvA = bf2f(half ? oA : mA);
        float wzvA = bf2f(half ? mA : oA);
        float xcvB = bf2f(half ? oB : mB);
        float wzvB = bf2f(half ? mB : oB);
        float uA = dtA * xcvA, uB = dtB * xcvB;
        f32x2 uA2 = {uA,uA}, uB2 = {uB,uB};
        f32x2 wzA2 = {wzvA,wzvA}, wzB2 = {wzvB,wzvB};
        f32x2 dtA2 = {dtA,dtA}, dtB2 = {dtB,dtB};
        // B/C vec4 loads shared between channels (same t, same s-range)
        f32x4 Bva = *(const f32x4*)&xd[24 + half*8];
        f32x4 Bvb = *(const f32x4*)&xd[28 + half*8];
        f32x4 Cva = *(const f32x4*)&xd[40 + half*8];
        f32x4 Cvb = *(const f32x4*)&xd[44 + half*8];
        #pragma unroll
        for (int j = 0; j < 4; j++){
            f32x2 Bj = (j < 2) ? f32x2{Bva[2*j], Bva[2*j+1]} : f32x2{Bvb[2*j-4], Bvb[2*j-3]};
            f32x2 Cj = (j < 2) ? f32x2{Cva[2*j], Cva[2*j+1]} : f32x2{Cvb[2*j-4], Cvb[2*j-3]};
            // channel A
            f32x2 argA = dtA2 * AvA[j];
            f32x2 dAA;
            dAA[0] = __builtin_amdgcn_exp2f(argA[0]);
            dAA[1] = __builtin_amdgcn_exp2f(argA[1]);
            hA[j] = dAA * hA[j] + uA2 * Bj;
            f32x2 CwA = Cj * wzA2;
            ysA2 += hA[j] * CwA;
            qA[j] = qA[j] * dAA;
            GA[j] += qA[j] * CwA;
            // channel B
            f32x2 argB = dtB2 * AvB[j];
            f32x2 dAB;
            dAB[0] = __builtin_amdgcn_exp2f(argB[0]);
            dAB[1] = __builtin_amdgcn_exp2f(argB[1]);
            hB[j] = dAB * hB[j] + uB2 * Bj;
            f32x2 CwB = Cj * wzB2;
            ysB2 += hB[j] * CwB;
            qB[j] = qB[j] * dAB;
            GB[j] += qB[j] * CwB;
        }
        sdwA += xcvA * wzvA;
        sdwB += xcvB * wzvB;
    }
    float ysA = ysA2[0] + ysA2[1] + (half ? 0.f : DvA * sdwA);
    float ysB = ysB2[0] + ysB2[1] + (half ? 0.f : DvB * sdwB);
    ysA += __shfl_xor(ysA, 1);
    ysB += __shfl_xor(ysB, 1);
    long fbA = ((long)(b*NCHUNK + c)*49)*768 + d;
    long fbB = fbA + 128;
    if (!half){ FX[fbA] = ysA; FX[fbB] = ysB; }
    #pragma unroll
    for (int j = 0; j < 4; j++){
        int sg = half*8 + 2*j;
        FX[fbA + (1+sg)*768]  = hA[j][0];  FX[fbA + (2+sg)*768]  = hA[j][1];
        FX[fbA + (17+sg)*768] = qA[j][0];  FX[fbA + (18+sg)*768] = qA[j][1];
        FX[fbA + (33+sg)*768] = GA[j][0];  FX[fbA + (34+sg)*768] = GA[j][1];
        FX[fbB + (1+sg)*768]  = hB[j][0];  FX[fbB + (2+sg)*768]  = hB[j][1];
        FX[fbB + (17+sg)*768] = qB[j][0];  FX[fbB + (18+sg)*768] = qB[j][1];
        FX[fbB + (33+sg)*768] = GB[j][0];  FX[fbB + (34+sg)*768] = GB[j][1];
    }
}

// ---------------- k8: scan pass 2 — stitch chunks (thread per (b,d,s)) ----
__global__ __launch_bounds__(256) void k_fix(char* ws){
    const float* FX = (const float*)(ws + O_FX);
    float* ymean = (float*)(ws + O_YMEAN);
    int tid = threadIdx.x;
    int dl = tid & 15, s = tid >> 4;
    int d = blockIdx.x * 16 + dl;
    int b = blockIdx.y;
    float Hrun = 0.f, ys = 0.f;
    for (int c = 0; c < NCHUNK; c++){
        long fb = ((long)(b*NCHUNK + c)*49)*768 + d;
        float Gs = FX[fb + (33+s)*768];
        float Hs = FX[fb + (1+s)*768];
        float qs = FX[fb + (17+s)*768];
        ys += Hrun * Gs;
        if (s == 0) ys += FX[fb];
        Hrun = Hs + qs * Hrun;
    }
    __shared__ float sR[256];
    sR[tid] = ys;
    __syncthreads();
    #pragma unroll
    for (int st = 8; st >= 1; st >>= 1){
        if (s < st) sR[tid] += sR[tid + st*16];
        __syncthreads();
    }
    if (s == 0) ymean[b*768 + d] = sR[dl] * (1.f/L_);
}

// ---------------- k9: head part 1: pooled -> h = pooled@W_fc + b_fc ------
__global__ __launch_bounds__(256) void k_head1(char* ws){
    const float* ymean = (const float*)(ws + O_YMEAN);
    const float* xmean = (const float*)(ws + O_XMEAN);
    const float* Wout = (const float*)(ws + O_WOUT);
    const float* Wfc = (const float*)(ws + O_WFC);
    const float* bfc = (const float*)(ws + O_BFC);
    float* hbuf = (float*)(ws + O_H);
    int b = blockIdx.x, tid = threadIdx.x;
    __shared__ float sY[768];
    __shared__ float sP[384];
    sY[tid] = ymean[b*768 + tid];
    sY[tid+256] = ymean[b*768 + tid + 256];
    sY[tid+512] = ymean[b*768 + tid + 512];
    __syncthreads();
    for (int d = tid; d < 384; d += 256){
        float v = xmean[b*384 + d];
        for (int i = 0; i < 768; i++) v += sY[i] * Wout[i*384 + d];
        sP[d] = v;
    }
    __syncthreads();
    float v = bfc[tid];
    for (int dd = 0; dd < 384; dd++) v += sP[dd] * Wfc[dd*256 + tid];
    hbuf[b*256 + tid] = v;
}

// ---------------- k10: head part 2: batchnorm + relu + classifier --------
__global__ __launch_bounds__(384) void k_head2(char* ws, void* out){
    const int flag = *(const int*)(ws + O_FLAG);
    const float* hbuf = (const float*)(ws + O_H);
    const float* gam = (const float*)(ws + O_GAM);
    const float* bet = (const float*)(ws + O_BET);
    const float* Wcls = (const float*)(ws + O_WCLS);
    const float* bcls = (const float*)(ws + O_BCLS);
    int tid = threadIdx.x;
    __shared__ float sH[8*256];
    if (tid < 256){
        float hv[8]; float mu = 0.f;
        #pragma unroll
        for (int b = 0; b < 8; b++){ hv[b] = hbuf[b*256 + tid]; mu += hv[b]; }
        mu *= 0.125f;
        float var = 0.f;
        #pragma unroll
        for (int b = 0; b < 8; b++){ float dv = hv[b]-mu; var += dv*dv; }
        var *= 0.125f;
        float rs = rsqrtf(var + 1e-5f);
        #pragma unroll
        for (int b = 0; b < 8; b++){
            float t = (hv[b]-mu)*rs*gam[tid] + bet[tid];
            sH[b*256 + tid] = t > 0.f ? t : 0.f;
        }
    }
    __syncthreads();
    if (tid < 320){
        int b = tid / 40, c = tid % 40;
        float acc = bcls[c];
        for (int j = 0; j < 256; j++) acc += sH[b*256 + j] * Wcls[j*40 + c];
        if (flag) ((ushort_t*)out)[b*40 + c] = f2bf(acc);
        else      ((float*)out)[b*40 + c] = acc;
    }
}

// ---------------- launch ----------------
extern "C" void kernel_launch(void* const* d_in, const int* in_sizes, int n_in,
                              void* d_out, int out_size, void* d_ws, size_t ws_size,
                              hipStream_t stream){
    (void)in_sizes; (void)n_in; (void)out_size; (void)ws_size;
    char* ws = (char*)d_ws;
    Ptrs ps;
    for (int i = 0; i < 17; i++) ps.p[i] = d_in[i];

    k_detect<<<1, 256, 0, stream>>>(d_in[0], ws);
    k_prep<<<(unsigned)((N_PREP + 255) / 256), 256, 0, stream>>>(ps, ws);
    k_rmsnorm<<<ML_, 128, 0, stream>>>(d_in[0], ws);
    k_xmean<<<dim3(8, 3, 16), 256, 0, stream>>>(d_in[0], ws);
    k_gemm1<<<dim3(ML_/128, 12), 256, 0, stream>>>(ws);
    k_conv<<<dim3(3, L_/8, B_), 256, 0, stream>>>(ws);
    k_xproj<<<ML_/128, 256, 0, stream>>>(ws);
    k_scan<<<dim3(3, NCHUNK, B_), 256, 0, stream>>>(ws);
    k_fix<<<dim3(48, B_), 256, 0, stream>>>(ws);
    k_head1<<<B_, 256, 0, stream>>>(ws);
    k_head2<<<1, 384, 0, stream>>>(ws, d_out);
}

// Round 7
// 482.085 us; speedup vs baseline: 4.6546x; 1.0555x over previous
//
#include <hip/hip_runtime.h>

typedef unsigned short ushort_t;
typedef unsigned int u32;
typedef float f32x4 __attribute__((ext_vector_type(4)));
typedef float f32x2 __attribute__((ext_vector_type(2)));
typedef __bf16 bf16x8 __attribute__((ext_vector_type(8)));

#define B_ 8
#define L_ 4096
#define D_ 384
#define DI_ 768
#define S_ 16
#define NC_ 40
#define ML_ (B_*L_)   // 32768 rows
#define NCHUNK 32
#define CL 128        // chunk length (L_/NCHUNK)

// ---------------- workspace layout (bytes) ----------------
// ~154 MB total. Aliasing:
//   XN lives in XC region (dead after gemm1, before conv writes XC);
//   XDBL lives at start of XP region (XP dead after conv);
//   FX (chunk summaries, 38.5 MB) lives in XP region after XDBL.
constexpr size_t au(size_t x){ return (x + 255) & ~size_t(255); }
constexpr size_t O_FLAG = 0;                                   // int
constexpr size_t O_LNW  = 256;                                 // 384 f32
constexpr size_t O_CONVW= au(O_LNW  + 384*4);                  // 3072 f32
constexpr size_t O_CONVB= au(O_CONVW+ 3072*4);                 // 768 f32
constexpr size_t O_WDT  = au(O_CONVB+ 768*4);                  // 18432 f32
constexpr size_t O_DTB  = au(O_WDT  + 18432*4);                // 768 f32
constexpr size_t O_A    = au(O_DTB  + 768*4);                  // 12288 f32 (A = -exp(A_log)*log2e)
constexpr size_t O_DSKIP= au(O_A    + 12288*4);                // 768 f32
constexpr size_t O_WOUT = au(O_DSKIP+ 768*4);                  // 294912 f32
constexpr size_t O_WFC  = au(O_WOUT + 294912*4);               // 98304 f32
constexpr size_t O_BFC  = au(O_WFC  + 98304*4);                // 256 f32
constexpr size_t O_GAM  = au(O_BFC  + 256*4);
constexpr size_t O_BET  = au(O_GAM  + 256*4);
constexpr size_t O_WCLS = au(O_BET  + 256*4);                  // 10240 f32
constexpr size_t O_BCLS = au(O_WCLS + 10240*4);                // 40 f32
constexpr size_t O_XMEAN= au(O_BCLS + 40*4);                   // 8*384 f32 (atomic acc; later sP in-place)
constexpr size_t O_YMEAN= au(O_XMEAN+ 3072*4);                 // 8*768 f32
constexpr size_t O_H    = au(O_YMEAN+ 6144*4);                 // 8*256 f32
constexpr size_t O_WINT = au(O_H    + 2048*4);                 // W_in^T  [1536][384] bf16
constexpr size_t O_WXT  = au(O_WINT + (size_t)589824*2);       // W_xproj^T padded [64][768] bf16
constexpr size_t O_XP   = au(O_WXT  + (size_t)49152*2);        // [32768][768] bf16
constexpr size_t O_XDBL = O_XP;                                // alias: [32768][56] f32 (after conv)
constexpr size_t O_FX   = au(O_XDBL + (size_t)ML_*56*4);       // [b][c][49][768] f32 chunk summaries
constexpr size_t FX_SZ  = (size_t)B_*NCHUNK*49*768*4;          // 38.5 MB
constexpr size_t O_Z    = au(O_XP   + (size_t)ML_*768*2);      // [32768][768] bf16 (holds silu(z))
constexpr size_t O_XCU  = au(O_Z    + (size_t)ML_*768*2);      // union region, 50.3 MB
constexpr size_t O_XN   = O_XCU;                               // [32768][384] bf16 (dead after gemm1)
constexpr size_t O_XC   = O_XCU;                               // [32768][768] bf16
constexpr size_t WS_NEED= O_XCU + (size_t)ML_*768*2;           // ~154 MB
static_assert(O_FX + FX_SZ <= O_Z, "FX must fit in dead XP tail");

// ---------------- helpers ----------------
__device__ inline float bf2f(ushort_t u){ return __uint_as_float(((u32)u) << 16); }
__device__ inline ushort_t f2bf(float f){
    u32 x = __float_as_uint(f);
    u32 r = (x + 0x7fffu + ((x >> 16) & 1u)) >> 16;   // RNE
    return (ushort_t)r;
}
__device__ inline float ldf(const void* p, long i, int flag){
    return flag ? bf2f(((const ushort_t*)p)[i]) : ((const float*)p)[i];
}
__device__ inline ushort_t ldbf(const void* p, long i, int flag){
    return flag ? ((const ushort_t*)p)[i] : f2bf(((const float*)p)[i]);
}
__device__ inline float sigm(float v){ return 1.f / (1.f + __expf(-v)); }

__device__ inline void gload_lds16(const void* g, void* l){
    __builtin_amdgcn_global_load_lds(
        (const __attribute__((address_space(1))) u32*)g,
        (__attribute__((address_space(3))) u32*)l, 16, 0, 0);
}

struct Ptrs { const void* p[17]; };

// ---------------- k0: dtype detect ----------------
__global__ void k_detect(const void* x, char* ws){
    __shared__ float s[256];
    int tid = threadIdx.x;
    s[tid] = fabsf(bf2f(((const ushort_t*)x)[tid]));
    __syncthreads();
    for (int st = 128; st > 0; st >>= 1){
        if (tid < st) s[tid] = fmaxf(s[tid], s[tid + st]);
        __syncthreads();
    }
    if (tid == 0) *(int*)(ws + O_FLAG) = (s[0] < 1e4f) ? 1 : 0;
}

// ---------------- k1: weight prep ----------------
#define N_PREP 1082792L
__global__ __launch_bounds__(256) void k_prep(Ptrs ps, char* ws){
    const int flag = *(const int*)(ws + O_FLAG);
    long o = (long)blockIdx.x * 256 + threadIdx.x;
    if (o < 384){ ((float*)(ws+O_LNW))[o]  = ldf(ps.p[1],o,flag); return; }  o -= 384;
    if (o < 3072){ ((float*)(ws+O_CONVW))[o]= ldf(ps.p[3],o,flag); return; } o -= 3072;
    if (o < 768){ ((float*)(ws+O_CONVB))[o]= ldf(ps.p[4],o,flag); return; }  o -= 768;
    if (o < 18432){ ((float*)(ws+O_WDT))[o]= ldf(ps.p[6],o,flag); return; }  o -= 18432;
    if (o < 768){ ((float*)(ws+O_DTB))[o]  = ldf(ps.p[7],o,flag); return; }  o -= 768;
    if (o < 768){ ((float*)(ws+O_DSKIP))[o]= ldf(ps.p[9],o,flag); return; }  o -= 768;
    if (o < 294912){ ((float*)(ws+O_WOUT))[o]= ldf(ps.p[10],o,flag); return; } o -= 294912;
    if (o < 98304){ ((float*)(ws+O_WFC))[o]= ldf(ps.p[11],o,flag); return; } o -= 98304;
    if (o < 256){ ((float*)(ws+O_BFC))[o]  = ldf(ps.p[12],o,flag); return; } o -= 256;
    if (o < 256){ ((float*)(ws+O_GAM))[o]  = ldf(ps.p[13],o,flag); return; } o -= 256;
    if (o < 256){ ((float*)(ws+O_BET))[o]  = ldf(ps.p[14],o,flag); return; } o -= 256;
    if (o < 10240){ ((float*)(ws+O_WCLS))[o]= ldf(ps.p[15],o,flag); return; } o -= 10240;
    if (o < 40){ ((float*)(ws+O_BCLS))[o]  = ldf(ps.p[16],o,flag); return; } o -= 40;
    // A = -exp(A_log) * log2(e)   (scan uses exp2)
    if (o < 12288){ ((float*)(ws+O_A))[o]  = -__expf(ldf(ps.p[8],o,flag)) * 1.4426950408889634f; return; } o -= 12288;
    if (o < 589824){                     // W_in [384,1536] -> WinT [1536][384]
        long n = o / 384, k = o % 384;
        ((ushort_t*)(ws+O_WINT))[o] = ldbf(ps.p[2], k*1536 + n, flag); return;
    } o -= 589824;
    if (o < 49152){                      // W_xproj [768,56] -> WxT [64][768], zero-pad n>=56
        long n = o / 768, k = o % 768;
        ((ushort_t*)(ws+O_WXT))[o] = (n < 56) ? ldbf(ps.p[5], k*56 + n, flag) : (ushort_t)0;
        return;
    } o -= 49152;
    if (o < 3072){ ((float*)(ws+O_XMEAN))[o] = 0.f; return; }
}

// ---------------- k2: RMSNorm -> xn (bf16), wave-per-row ----------------
// R6: old version used 128-thr blocks with a 7-barrier tree reduce per row
// (32768 blocks). New: 4 rows per 256-thr block, one wave per row, 6-step
// shfl_xor butterfly, ZERO barriers, zero LDS. Same math, same order class.
__global__ __launch_bounds__(256) void k_rmsnorm(const void* x, char* ws){
    const int flag = *(const int*)(ws + O_FLAG);
    const float* lnw = (const float*)(ws + O_LNW);
    ushort_t* xn = (ushort_t*)(ws + O_XN);
    int tid = threadIdx.x;
    int lane = tid & 63;
    long row = (long)blockIdx.x * 4 + (tid >> 6);
    float v[6];
    if (flag){
        const ushort_t* xb = (const ushort_t*)x + row*384;
        #pragma unroll
        for (int k = 0; k < 6; k++) v[k] = bf2f(xb[lane + k*64]);
    } else {
        const float* xf = (const float*)x + row*384;
        #pragma unroll
        for (int k = 0; k < 6; k++) v[k] = xf[lane + k*64];
    }
    float ss = 0.f;
    #pragma unroll
    for (int k = 0; k < 6; k++) ss += v[k]*v[k];
    #pragma unroll
    for (int m = 1; m < 64; m <<= 1) ss += __shfl_xor(ss, m);
    float scale = rsqrtf(ss * (1.f/384.f) + 1e-5f);
    #pragma unroll
    for (int k = 0; k < 6; k++)
        xn[row*384 + lane + k*64] = f2bf(v[k] * scale * lnw[lane + k*64]);
}

// ---------------- k3: xmean[b,d] = mean_L x ----------------
__global__ __launch_bounds__(256) void k_xmean(const void* x, char* ws){
    const int flag = *(const int*)(ws + O_FLAG);
    float* xmean = (float*)(ws + O_XMEAN);
    int b = blockIdx.x, d0 = blockIdx.y*128, l0 = blockIdx.z*256;
    int tid = threadIdx.x, dl = tid & 127, lh = tid >> 7;
    float acc = 0.f;
    if (flag){
        const ushort_t* xb = (const ushort_t*)x;
        for (int l = l0 + lh; l < l0 + 256; l += 2)
            acc += bf2f(xb[((long)b*L_ + l)*384 + d0 + dl]);
    } else {
        const float* xf = (const float*)x;
        for (int l = l0 + lh; l < l0 + 256; l += 2)
            acc += xf[((long)b*L_ + l)*384 + d0 + dl];
    }
    __shared__ float s[256];
    s[tid] = acc; __syncthreads();
    if (tid < 128)
        atomicAdd(&xmean[b*384 + d0 + dl], (s[tid] + s[tid+128]) * (1.f/L_));
}

// ---------------- k4: GEMM1  xn @ W_in -> xp | silu(z) ---------
__global__ __launch_bounds__(256) void k_gemm1(char* ws){
    const ushort_t* xn = (const ushort_t*)(ws + O_XN);
    const ushort_t* wT = (const ushort_t*)(ws + O_WINT);
    ushort_t* xp = (ushort_t*)(ws + O_XP);
    ushort_t* zz = (ushort_t*)(ws + O_Z);
    __shared__ ushort_t sA[128*32];
    __shared__ ushort_t sB[128*32];
    int tid = threadIdx.x, w = tid >> 6, l = tid & 63;
    long m0 = (long)blockIdx.x * 128;
    int n0 = blockIdx.y * 128;
    f32x4 acc[4][4] = {};
    int lr = l >> 2, lk = (l & 3) * 8;
    const ushort_t* gA = xn + (m0 + w*16 + lr)*384 + lk;
    const ushort_t* gB = wT + ((long)(n0 + w*16 + lr))*384 + lk;
    ushort_t* lA = &sA[w*16*32];
    ushort_t* lB = &sB[w*16*32];
    int wm = w & 1, wn = w >> 1;
    int arow = wm*64 + (l & 15);
    int brow = wn*64 + (l & 15);
    int koff = (l >> 4) * 8;
    for (int kc = 0; kc < 12; kc++){
        int k0 = kc * 32;
        gload_lds16(gA + k0,           lA);
        gload_lds16(gA + k0 + 64*384,  lA + 64*32);
        gload_lds16(gB + k0,           lB);
        gload_lds16(gB + k0 + 64*384,  lB + 64*32);
        __syncthreads();
        bf16x8 af[4], bfv[4];
        #pragma unroll
        for (int i = 0; i < 4; i++){
            af[i]  = *(const bf16x8*)&sA[(arow + i*16)*32 + koff];
            bfv[i] = *(const bf16x8*)&sB[(brow + i*16)*32 + koff];
        }
        #pragma unroll
        for (int mb = 0; mb < 4; mb++)
            #pragma unroll
            for (int nb = 0; nb < 4; nb++)
                acc[mb][nb] = __builtin_amdgcn_mfma_f32_16x16x32_bf16(af[mb], bfv[nb], acc[mb][nb], 0, 0, 0);
        __syncthreads();
    }
    ushort_t* outp; int nc0; bool isz;
    if (n0 < 768){ outp = xp; nc0 = n0; isz = false; }
    else { outp = zz; nc0 = n0 - 768; isz = true; }
    int rbase = (l >> 4) * 4, cl = l & 15;
    #pragma unroll
    for (int mb = 0; mb < 4; mb++)
        #pragma unroll
        for (int nb = 0; nb < 4; nb++){
            long row = m0 + wm*64 + mb*16 + rbase;
            int col = nc0 + wn*64 + nb*16 + cl;
            #pragma unroll
            for (int r = 0; r < 4; r++){
                float v = acc[mb][nb][r];
                if (isz) v = v * sigm(v);        // fused silu for z
                outp[(row + r)*768 + col] = f2bf(v);
            }
        }
}

// ---------------- k5: causal depthwise conv K=4 + SiLU ----------------
__global__ __launch_bounds__(256) void k_conv(char* ws){
    const ushort_t* xp = (const ushort_t*)(ws + O_XP);
    ushort_t* xc = (ushort_t*)(ws + O_XC);
    const float* cw = (const float*)(ws + O_CONVW);
    const float* cb = (const float*)(ws + O_CONVB);
    int d = blockIdx.x*256 + threadIdx.x;
    int t0 = blockIdx.y * 8;
    int b = blockIdx.z;
    long rbase = (long)b * L_;
    float w0 = cw[d*4], w1 = cw[d*4+1], w2 = cw[d*4+2], w3 = cw[d*4+3];
    float bias = cb[d];
    float xv[11];
    #pragma unroll
    for (int i = 0; i < 11; i++){
        int t = t0 - 3 + i;
        xv[i] = (t >= 0) ? bf2f(xp[(rbase + t)*768 + d]) : 0.f;
    }
    #pragma unroll
    for (int tt = 0; tt < 8; tt++){
        float v = bias + xv[tt]*w0 + xv[tt+1]*w1 + xv[tt+2]*w2 + xv[tt+3]*w3;
        v = v * sigm(v);
        xc[(rbase + t0 + tt)*768 + d] = f2bf(v);
    }
}

// ---------------- k6: xproj  xc @ W_xproj -> x_dbl[32768,56] ----
__global__ __launch_bounds__(256) void k_xproj(char* ws){
    const ushort_t* xc = (const ushort_t*)(ws + O_XC);
    const ushort_t* wT = (const ushort_t*)(ws + O_WXT);
    float* xdbl = (float*)(ws + O_XDBL);
    __shared__ ushort_t sA[128*32];
    __shared__ ushort_t sB[64*32];
    int tid = threadIdx.x, w = tid >> 6, l = tid & 63;
    long m0 = (long)blockIdx.x * 128;
    f32x4 acc[2][4] = {};
    int lr = l >> 2, lk = (l & 3) * 8;
    const ushort_t* gA = xc + (m0 + w*16 + lr)*768 + lk;
    const ushort_t* gB = wT + ((long)(w*16 + lr))*768 + lk;
    ushort_t* lA = &sA[w*16*32];
    ushort_t* lB = &sB[w*16*32];
    int arow0 = w*32 + (l & 15);
    int brow = l & 15;
    int koff = (l >> 4) * 8;
    for (int kc = 0; kc < 24; kc++){
        int k0 = kc * 32;
        gload_lds16(gA + k0,           lA);
        gload_lds16(gA + k0 + 64*768,  lA + 64*32);
        gload_lds16(gB + k0,           lB);
        __syncthreads();
        bf16x8 af[2], bfv[4];
        af[0] = *(const bf16x8*)&sA[arow0*32 + koff];
        af[1] = *(const bf16x8*)&sA[(arow0+16)*32 + koff];
        #pragma unroll
        for (int nb = 0; nb < 4; nb++)
            bfv[nb] = *(const bf16x8*)&sB[(nb*16 + brow)*32 + koff];
        #pragma unroll
        for (int mb = 0; mb < 2; mb++)
            #pragma unroll
            for (int nb = 0; nb < 4; nb++)
                acc[mb][nb] = __builtin_amdgcn_mfma_f32_16x16x32_bf16(af[mb], bfv[nb], acc[mb][nb], 0, 0, 0);
        __syncthreads();
    }
    int rbase = (l >> 4) * 4, cl = l & 15;
    #pragma unroll
    for (int mb = 0; mb < 2; mb++)
        #pragma unroll
        for (int nb = 0; nb < 4; nb++){
            int col = nb*16 + cl;
            if (col < 56){
                long row = m0 + w*32 + mb*16 + rbase;
                #pragma unroll
                for (int r = 0; r < 4; r++)
                    xdbl[(row + r)*56 + col] = acc[mb][nb][r];
            }
        }
}

// ---------------- k7: chunk-parallel selective scan (pass 1) --------------
// v10 (unchanged from R5; R6 post-mortem: duration ~148us and VALUBusy ~65%
// are invariant across occupancy 26-39% and ILP arrangements -> k_scan is
// bounded by total VALU+trans instruction issue (~96us of issue). Further
// gains need instruction-count cuts (packed-op verification requires
// disasm). Parked; this round targets the non-scan 360us.)
__global__ __launch_bounds__(256, 3) void k_scan(char* ws){
    const ushort_t* xc = (const ushort_t*)(ws + O_XC);
    const ushort_t* wz = (const ushort_t*)(ws + O_Z);      // silu(z)
    const float* xdbl = (const float*)(ws + O_XDBL);
    const float* Ag = (const float*)(ws + O_A);            // -exp(A_log)*log2e
    const float* Dsk = (const float*)(ws + O_DSKIP);
    const float* Wdt = (const float*)(ws + O_WDT);
    const float* dtb = (const float*)(ws + O_DTB);
    float* FX = (float*)(ws + O_FX);
    int tid = threadIdx.x;
    int half = tid & 1, p = tid >> 1;          // pair = lanes 2k,2k+1; 128 pairs
    int d = blockIdx.x * 256 + p;              // channel A; channel B = d+128
    int c = blockIdx.y, b = blockIdx.z;
    long row0 = (long)b * L_ + (long)c * CL;

    __shared__ float sXD[CL*56];               // 28 KB: whole chunk's xdbl
    {
        const f32x4* src = (const f32x4*)(xdbl + row0*56);   // 1792 vec4
        f32x4* dst = (f32x4*)sXD;
        #pragma unroll
        for (int i = 0; i < 7; i++) dst[tid + i*256] = src[tid + i*256];
    }

    f32x2 wdtA[6], wdtB[6];
    #pragma unroll
    for (int k = 0; k < 6; k++){
        wdtA[k][0] = Wdt[(half*12 + 2*k    )*768 + d];
        wdtA[k][1] = Wdt[(half*12 + 2*k + 1)*768 + d];
        wdtB[k][0] = Wdt[(half*12 + 2*k    )*768 + d + 128];
        wdtB[k][1] = Wdt[(half*12 + 2*k + 1)*768 + d + 128];
    }
    float dbiasA = half ? 0.f : dtb[d];
    float dbiasB = half ? 0.f : dtb[d + 128];
    f32x2 AvA[4], AvB[4];
    #pragma unroll
    for (int j = 0; j < 4; j++){
        AvA[j][0] = Ag[d*16 + half*8 + 2*j];
        AvA[j][1] = Ag[d*16 + half*8 + 2*j + 1];
        AvB[j][0] = Ag[(d+128)*16 + half*8 + 2*j];
        AvB[j][1] = Ag[(d+128)*16 + half*8 + 2*j + 1];
    }
    float DvA = Dsk[d], DvB = Dsk[d + 128];
    __syncthreads();                           // the only barrier

    f32x2 hA[4], qA[4], GA[4], hB[4], qB[4], GB[4];
    #pragma unroll
    for (int j = 0; j < 4; j++){
        hA[j] = f32x2{0.f,0.f}; GA[j] = f32x2{0.f,0.f}; qA[j] = f32x2{1.f,1.f};
        hB[j] = f32x2{0.f,0.f}; GB[j] = f32x2{0.f,0.f}; qB[j] = f32x2{1.f,1.f};
    }
    f32x2 ysA2 = {0.f,0.f}, ysB2 = {0.f,0.f};
    float sdwA = 0.f, sdwB = 0.f;

    const ushort_t* gx = (half ? wz : xc) + row0*768 + d;   // parity-split stream

    #pragma unroll 4
    for (int t = 0; t < CL; t++){
        ushort_t mA = gx[t*768];
        ushort_t mB = gx[t*768 + 128];
        const float* xd = &sXD[t*56];
        // dt dot for both channels — xd vec4 loads shared
        f32x2 accA = {dbiasA, 0.f}, accB = {dbiasB, 0.f};
        #pragma unroll
        for (int j = 0; j < 3; j++){
            f32x4 v = *(const f32x4*)&xd[half*12 + j*4];
            f32x2 vlo = {v[0], v[1]}, vhi = {v[2], v[3]};
            accA += vlo * wdtA[2*j];  accA += vhi * wdtA[2*j + 1];
            accB += vlo * wdtB[2*j];  accB += vhi * wdtB[2*j + 1];
        }
        float dpA = accA[0] + accA[1], dpB = accB[0] + accB[1];
        float dtA = dpA + __shfl_xor(dpA, 1);
        float dtB = dpB + __shfl_xor(dpB, 1);
        // softplus both
        float eA = __builtin_amdgcn_exp2f(dtA * 1.4426950408889634f);
        float sA_ = 0.69314718055994531f * __builtin_amdgcn_logf(1.f + eA);
        dtA = (dtA > 20.f) ? dtA : sA_;
        float eB = __builtin_amdgcn_exp2f(dtB * 1.4426950408889634f);
        float sB_ = 0.69314718055994531f * __builtin_amdgcn_logf(1.f + eB);
        dtB = (dtB > 20.f) ? dtB : sB_;
        // packed xc/z exchange for both channels in ONE shuffle
        u32 pk = (u32)mA | ((u32)mB << 16);
        u32 other = (u32)__shfl_xor((int)pk, 1);
        ushort_t oA = (ushort_t)(other & 0xffffu), oB = (ushort_t)(other >> 16);
        float xcvA = bf2f(half ? oA : mA);
        float wzvA = bf2f(half ? mA : oA);
        float xcvB = bf2f(half ? oB : mB);
        float wzvB = bf2f(half ? mB : oB);
        float uA = dtA * xcvA, uB = dtB * xcvB;
        f32x2 uA2 = {uA,uA}, uB2 = {uB,uB};
        f32x2 wzA2 = {wzvA,wzvA}, wzB2 = {wzvB,wzvB};
        f32x2 dtA2 = {dtA,dtA}, dtB2 = {dtB,dtB};
        // B/C vec4 loads shared between channels (same t, same s-range)
        f32x4 Bva = *(const f32x4*)&xd[24 + half*8];
        f32x4 Bvb = *(const f32x4*)&xd[28 + half*8];
        f32x4 Cva = *(const f32x4*)&xd[40 + half*8];
        f32x4 Cvb = *(const f32x4*)&xd[44 + half*8];
        #pragma unroll
        for (int j = 0; j < 4; j++){
            f32x2 Bj = (j < 2) ? f32x2{Bva[2*j], Bva[2*j+1]} : f32x2{Bvb[2*j-4], Bvb[2*j-3]};
            f32x2 Cj = (j < 2) ? f32x2{Cva[2*j], Cva[2*j+1]} : f32x2{Cvb[2*j-4], Cvb[2*j-3]};
            // channel A
            f32x2 argA = dtA2 * AvA[j];
            f32x2 dAA;
            dAA[0] = __builtin_amdgcn_exp2f(argA[0]);
            dAA[1] = __builtin_amdgcn_exp2f(argA[1]);
            hA[j] = dAA * hA[j] + uA2 * Bj;
            f32x2 CwA = Cj * wzA2;
            ysA2 += hA[j] * CwA;
            qA[j] = qA[j] * dAA;
            GA[j] += qA[j] * CwA;
            // channel B
            f32x2 argB = dtB2 * AvB[j];
            f32x2 dAB;
            dAB[0] = __builtin_amdgcn_exp2f(argB[0]);
            dAB[1] = __builtin_amdgcn_exp2f(argB[1]);
            hB[j] = dAB * hB[j] + uB2 * Bj;
            f32x2 CwB = Cj * wzB2;
            ysB2 += hB[j] * CwB;
            qB[j] = qB[j] * dAB;
            GB[j] += qB[j] * CwB;
        }
        sdwA += xcvA * wzvA;
        sdwB += xcvB * wzvB;
    }
    float ysA = ysA2[0] + ysA2[1] + (half ? 0.f : DvA * sdwA);
    float ysB = ysB2[0] + ysB2[1] + (half ? 0.f : DvB * sdwB);
    ysA += __shfl_xor(ysA, 1);
    ysB += __shfl_xor(ysB, 1);
    long fbA = ((long)(b*NCHUNK + c)*49)*768 + d;
    long fbB = fbA + 128;
    if (!half){ FX[fbA] = ysA; FX[fbB] = ysB; }
    #pragma unroll
    for (int j = 0; j < 4; j++){
        int sg = half*8 + 2*j;
        FX[fbA + (1+sg)*768]  = hA[j][0];  FX[fbA + (2+sg)*768]  = hA[j][1];
        FX[fbA + (17+sg)*768] = qA[j][0];  FX[fbA + (18+sg)*768] = qA[j][1];
        FX[fbA + (33+sg)*768] = GA[j][0];  FX[fbA + (34+sg)*768] = GA[j][1];
        FX[fbB + (1+sg)*768]  = hB[j][0];  FX[fbB + (2+sg)*768]  = hB[j][1];
        FX[fbB + (17+sg)*768] = qB[j][0];  FX[fbB + (18+sg)*768] = qB[j][1];
        FX[fbB + (33+sg)*768] = GB[j][0];  FX[fbB + (34+sg)*768] = GB[j][1];
    }
}

// ---------------- k8: scan pass 2 — stitch chunks (thread per (b,d,s)) ----
__global__ __launch_bounds__(256) void k_fix(char* ws){
    const float* FX = (const float*)(ws + O_FX);
    float* ymean = (float*)(ws + O_YMEAN);
    int tid = threadIdx.x;
    int dl = tid & 15, s = tid >> 4;
    int d = blockIdx.x * 16 + dl;
    int b = blockIdx.y;
    float Hrun = 0.f, ys = 0.f;
    for (int c = 0; c < NCHUNK; c++){
        long fb = ((long)(b*NCHUNK + c)*49)*768 + d;
        float Gs = FX[fb + (33+s)*768];
        float Hs = FX[fb + (1+s)*768];
        float qs = FX[fb + (17+s)*768];
        ys += Hrun * Gs;
        if (s == 0) ys += FX[fb];
        Hrun = Hs + qs * Hrun;
    }
    __shared__ float sR[256];
    sR[tid] = ys;
    __syncthreads();
    #pragma unroll
    for (int st = 8; st >= 1; st >>= 1){
        if (s < st) sR[tid] += sR[tid + st*16];
        __syncthreads();
    }
    if (s == 0) ymean[b*768 + d] = sR[dl] * (1.f/L_);
}

// ---------------- k9a: sP = xmean + ymean @ Wout  (in-place into xmean) ---
// R6: old k_head1 ran this matvec on 8 blocks (248 CUs idle), 768-deep
// serial per thread. Now 24 blocks (8b x 3 d-tiles), 2 threads per d each
// summing 384 i's, pair-combined via shfl. xmean is dead after this except
// as sP input to k_head1 -> accumulate in place (disjoint (b,d) per block).
__global__ __launch_bounds__(256) void k_head1a(char* ws){
    const float* ymean = (const float*)(ws + O_YMEAN);
    const float* Wout = (const float*)(ws + O_WOUT);
    float* xmean = (float*)(ws + O_XMEAN);     // becomes sP
    int b = blockIdx.x;
    int d = blockIdx.y*128 + (threadIdx.x >> 1);
    int half = threadIdx.x & 1;
    const float* ym = ymean + b*768 + half*384;
    const float* wo = Wout + (long)half*384*384 + d;
    float acc = 0.f;
    #pragma unroll 8
    for (int i = 0; i < 384; i++)
        acc += ym[i] * wo[i*384];
    acc += __shfl_xor(acc, 1);
    if (!half) xmean[b*384 + d] += acc;
}

// ---------------- k9b: h = sP @ W_fc + b_fc ------------------------------
__global__ __launch_bounds__(256) void k_head1(char* ws){
    const float* sP = (const float*)(ws + O_XMEAN);
    const float* Wfc = (const float*)(ws + O_WFC);
    const float* bfc = (const float*)(ws + O_BFC);
    float* hbuf = (float*)(ws + O_H);
    int b = blockIdx.x, tid = threadIdx.x;
    __shared__ float sPl[384];
    for (int i = tid; i < 384; i += 256) sPl[i] = sP[b*384 + i];
    __syncthreads();
    float v = bfc[tid];
    #pragma unroll 8
    for (int dd = 0; dd < 384; dd++) v += sPl[dd] * Wfc[dd*256 + tid];
    hbuf[b*256 + tid] = v;
}

// ---------------- k10: head part 2: batchnorm + relu + classifier --------
__global__ __launch_bounds__(384) void k_head2(char* ws, void* out){
    const int flag = *(const int*)(ws + O_FLAG);
    const float* hbuf = (const float*)(ws + O_H);
    const float* gam = (const float*)(ws + O_GAM);
    const float* bet = (const float*)(ws + O_BET);
    const float* Wcls = (const float*)(ws + O_WCLS);
    const float* bcls = (const float*)(ws + O_BCLS);
    int tid = threadIdx.x;
    __shared__ float sH[8*256];
    if (tid < 256){
        float hv[8]; float mu = 0.f;
        #pragma unroll
        for (int b = 0; b < 8; b++){ hv[b] = hbuf[b*256 + tid]; mu += hv[b]; }
        mu *= 0.125f;
        float var = 0.f;
        #pragma unroll
        for (int b = 0; b < 8; b++){ float dv = hv[b]-mu; var += dv*dv; }
        var *= 0.125f;
        float rs = rsqrtf(var + 1e-5f);
        #pragma unroll
        for (int b = 0; b < 8; b++){
            float t = (hv[b]-mu)*rs*gam[tid] + bet[tid];
            sH[b*256 + tid] = t > 0.f ? t : 0.f;
        }
    }
    __syncthreads();
    if (tid < 320){
        int b = tid / 40, c = tid % 40;
        float acc = bcls[c];
        for (int j = 0; j < 256; j++) acc += sH[b*256 + j] * Wcls[j*40 + c];
        if (flag) ((ushort_t*)out)[b*40 + c] = f2bf(acc);
        else      ((float*)out)[b*40 + c] = acc;
    }
}

// ---------------- launch ----------------
extern "C" void kernel_launch(void* const* d_in, const int* in_sizes, int n_in,
                              void* d_out, int out_size, void* d_ws, size_t ws_size,
                              hipStream_t stream){
    (void)in_sizes; (void)n_in; (void)out_size; (void)ws_size;
    char* ws = (char*)d_ws;
    Ptrs ps;
    for (int i = 0; i < 17; i++) ps.p[i] = d_in[i];

    k_detect<<<1, 256, 0, stream>>>(d_in[0], ws);
    k_prep<<<(unsigned)((N_PREP + 255) / 256), 256, 0, stream>>>(ps, ws);
    k_rmsnorm<<<ML_/4, 256, 0, stream>>>(d_in[0], ws);
    k_xmean<<<dim3(8, 3, 16), 256, 0, stream>>>(d_in[0], ws);
    k_gemm1<<<dim3(ML_/128, 12), 256, 0, stream>>>(ws);
    k_conv<<<dim3(3, L_/8, B_), 256, 0, stream>>>(ws);
    k_xproj<<<ML_/128, 256, 0, stream>>>(ws);
    k_scan<<<dim3(3, NCHUNK, B_), 256, 0, stream>>>(ws);
    k_fix<<<dim3(48, B_), 256, 0, stream>>>(ws);
    k_head1a<<<dim3(8, 3), 256, 0, stream>>>(ws);
    k_head1<<<B_, 256, 0, stream>>>(ws);
    k_head2<<<1, 384, 0, stream>>>(ws, d_out);
}

// Round 8
// 453.623 us; speedup vs baseline: 4.9466x; 1.0627x over previous
//
#include <hip/hip_runtime.h>

typedef unsigned short ushort_t;
typedef unsigned int u32;
typedef float f32x4 __attribute__((ext_vector_type(4)));
typedef float f32x2 __attribute__((ext_vector_type(2)));
typedef __bf16 bf16x8 __attribute__((ext_vector_type(8)));
typedef unsigned short us4 __attribute__((ext_vector_type(4)));

#define B_ 8
#define L_ 4096
#define D_ 384
#define DI_ 768
#define S_ 16
#define NC_ 40
#define ML_ (B_*L_)   // 32768 rows
#define NCHUNK 32
#define CL 128        // chunk length (L_/NCHUNK)

// ---------------- workspace layout (bytes) ----------------
// ~154 MB total. Aliasing:
//   XN lives in XC region (dead after gemm1, before conv writes XC);
//   XDBL lives at start of XP region (XP dead after conv);
//   FX (chunk summaries, 38.5 MB) lives in XP region after XDBL.
constexpr size_t au(size_t x){ return (x + 255) & ~size_t(255); }
constexpr size_t O_FLAG = 0;                                   // int
constexpr size_t O_LNW  = 256;                                 // 384 f32
constexpr size_t O_CONVW= au(O_LNW  + 384*4);                  // 3072 f32
constexpr size_t O_CONVB= au(O_CONVW+ 3072*4);                 // 768 f32
constexpr size_t O_WDT  = au(O_CONVB+ 768*4);                  // 18432 f32
constexpr size_t O_DTB  = au(O_WDT  + 18432*4);                // 768 f32
constexpr size_t O_A    = au(O_DTB  + 768*4);                  // 12288 f32 (A = -exp(A_log)*log2e)
constexpr size_t O_DSKIP= au(O_A    + 12288*4);                // 768 f32
constexpr size_t O_WOUT = au(O_DSKIP+ 768*4);                  // 294912 f32
constexpr size_t O_WFC  = au(O_WOUT + 294912*4);               // 98304 f32
constexpr size_t O_BFC  = au(O_WFC  + 98304*4);                // 256 f32
constexpr size_t O_GAM  = au(O_BFC  + 256*4);
constexpr size_t O_BET  = au(O_GAM  + 256*4);
constexpr size_t O_WCLS = au(O_BET  + 256*4);                  // 10240 f32
constexpr size_t O_BCLS = au(O_WCLS + 10240*4);                // 40 f32
constexpr size_t O_XMEAN= au(O_BCLS + 40*4);                   // 8*384 f32 (atomic acc; later sP in-place)
constexpr size_t O_YMEAN= au(O_XMEAN+ 3072*4);                 // 8*768 f32
constexpr size_t O_H    = au(O_YMEAN+ 6144*4);                 // 8*256 f32
constexpr size_t O_WINT = au(O_H    + 2048*4);                 // W_in^T  [1536][384] bf16
constexpr size_t O_WXT  = au(O_WINT + (size_t)589824*2);       // W_xproj^T padded [64][768] bf16
constexpr size_t O_XP   = au(O_WXT  + (size_t)49152*2);        // [32768][768] bf16
constexpr size_t O_XDBL = O_XP;                                // alias: [32768][56] f32 (after conv)
constexpr size_t O_FX   = au(O_XDBL + (size_t)ML_*56*4);       // [b][c][49][768] f32 chunk summaries
constexpr size_t FX_SZ  = (size_t)B_*NCHUNK*49*768*4;          // 38.5 MB
constexpr size_t O_Z    = au(O_XP   + (size_t)ML_*768*2);      // [32768][768] bf16 (holds silu(z))
constexpr size_t O_XCU  = au(O_Z    + (size_t)ML_*768*2);      // union region, 50.3 MB
constexpr size_t O_XN   = O_XCU;                               // [32768][384] bf16 (dead after gemm1)
constexpr size_t O_XC   = O_XCU;                               // [32768][768] bf16
constexpr size_t WS_NEED= O_XCU + (size_t)ML_*768*2;           // ~154 MB
static_assert(O_FX + FX_SZ <= O_Z, "FX must fit in dead XP tail");

// ---------------- helpers ----------------
__device__ inline float bf2f(ushort_t u){ return __uint_as_float(((u32)u) << 16); }
__device__ inline ushort_t f2bf(float f){
    u32 x = __float_as_uint(f);
    u32 r = (x + 0x7fffu + ((x >> 16) & 1u)) >> 16;   // RNE
    return (ushort_t)r;
}
__device__ inline float ldf(const void* p, long i, int flag){
    return flag ? bf2f(((const ushort_t*)p)[i]) : ((const float*)p)[i];
}
__device__ inline ushort_t ldbf(const void* p, long i, int flag){
    return flag ? ((const ushort_t*)p)[i] : f2bf(((const float*)p)[i]);
}
__device__ inline float sigm(float v){ return 1.f / (1.f + __expf(-v)); }

__device__ inline void gload_lds16(const void* g, void* l){
    __builtin_amdgcn_global_load_lds(
        (const __attribute__((address_space(1))) u32*)g,
        (__attribute__((address_space(3))) u32*)l, 16, 0, 0);
}

struct Ptrs { const void* p[17]; };

// ---------------- k0: dtype detect ----------------
__global__ void k_detect(const void* x, char* ws){
    __shared__ float s[256];
    int tid = threadIdx.x;
    s[tid] = fabsf(bf2f(((const ushort_t*)x)[tid]));
    __syncthreads();
    for (int st = 128; st > 0; st >>= 1){
        if (tid < st) s[tid] = fmaxf(s[tid], s[tid + st]);
        __syncthreads();
    }
    if (tid == 0) *(int*)(ws + O_FLAG) = (s[0] < 1e4f) ? 1 : 0;
}

// ---------------- k1: weight prep ----------------
#define N_PREP 1082792L
__global__ __launch_bounds__(256) void k_prep(Ptrs ps, char* ws){
    const int flag = *(const int*)(ws + O_FLAG);
    long o = (long)blockIdx.x * 256 + threadIdx.x;
    if (o < 384){ ((float*)(ws+O_LNW))[o]  = ldf(ps.p[1],o,flag); return; }  o -= 384;
    if (o < 3072){ ((float*)(ws+O_CONVW))[o]= ldf(ps.p[3],o,flag); return; } o -= 3072;
    if (o < 768){ ((float*)(ws+O_CONVB))[o]= ldf(ps.p[4],o,flag); return; }  o -= 768;
    if (o < 18432){ ((float*)(ws+O_WDT))[o]= ldf(ps.p[6],o,flag); return; }  o -= 18432;
    if (o < 768){ ((float*)(ws+O_DTB))[o]  = ldf(ps.p[7],o,flag); return; }  o -= 768;
    if (o < 768){ ((float*)(ws+O_DSKIP))[o]= ldf(ps.p[9],o,flag); return; }  o -= 768;
    if (o < 294912){ ((float*)(ws+O_WOUT))[o]= ldf(ps.p[10],o,flag); return; } o -= 294912;
    if (o < 98304){ ((float*)(ws+O_WFC))[o]= ldf(ps.p[11],o,flag); return; } o -= 98304;
    if (o < 256){ ((float*)(ws+O_BFC))[o]  = ldf(ps.p[12],o,flag); return; } o -= 256;
    if (o < 256){ ((float*)(ws+O_GAM))[o]  = ldf(ps.p[13],o,flag); return; } o -= 256;
    if (o < 256){ ((float*)(ws+O_BET))[o]  = ldf(ps.p[14],o,flag); return; } o -= 256;
    if (o < 10240){ ((float*)(ws+O_WCLS))[o]= ldf(ps.p[15],o,flag); return; } o -= 10240;
    if (o < 40){ ((float*)(ws+O_BCLS))[o]  = ldf(ps.p[16],o,flag); return; } o -= 40;
    // A = -exp(A_log) * log2(e)   (scan uses exp2)
    if (o < 12288){ ((float*)(ws+O_A))[o]  = -__expf(ldf(ps.p[8],o,flag)) * 1.4426950408889634f; return; } o -= 12288;
    if (o < 589824){                     // W_in [384,1536] -> WinT [1536][384]
        long n = o / 384, k = o % 384;
        ((ushort_t*)(ws+O_WINT))[o] = ldbf(ps.p[2], k*1536 + n, flag); return;
    } o -= 589824;
    if (o < 49152){                      // W_xproj [768,56] -> WxT [64][768], zero-pad n>=56
        long n = o / 768, k = o % 768;
        ((ushort_t*)(ws+O_WXT))[o] = (n < 56) ? ldbf(ps.p[5], k*56 + n, flag) : (ushort_t)0;
        return;
    } o -= 49152;
    if (o < 3072){ ((float*)(ws+O_XMEAN))[o] = 0.f; return; }
}

// ---------------- k2: RMSNorm -> xn (bf16), wave-per-row ----------------
__global__ __launch_bounds__(256) void k_rmsnorm(const void* x, char* ws){
    const int flag = *(const int*)(ws + O_FLAG);
    const float* lnw = (const float*)(ws + O_LNW);
    ushort_t* xn = (ushort_t*)(ws + O_XN);
    int tid = threadIdx.x;
    int lane = tid & 63;
    long row = (long)blockIdx.x * 4 + (tid >> 6);
    float v[6];
    if (flag){
        const ushort_t* xb = (const ushort_t*)x + row*384;
        #pragma unroll
        for (int k = 0; k < 6; k++) v[k] = bf2f(xb[lane + k*64]);
    } else {
        const float* xf = (const float*)x + row*384;
        #pragma unroll
        for (int k = 0; k < 6; k++) v[k] = xf[lane + k*64];
    }
    float ss = 0.f;
    #pragma unroll
    for (int k = 0; k < 6; k++) ss += v[k]*v[k];
    #pragma unroll
    for (int m = 1; m < 64; m <<= 1) ss += __shfl_xor(ss, m);
    float scale = rsqrtf(ss * (1.f/384.f) + 1e-5f);
    #pragma unroll
    for (int k = 0; k < 6; k++)
        xn[row*384 + lane + k*64] = f2bf(v[k] * scale * lnw[lane + k*64]);
}

// ---------------- k3: xmean[b,d] = mean_L x ----------------
// R7: grid z 16->64 (64 l's per block, 32 iters/thread): 1536 blocks = 6/CU
// (was 1.5/CU, latency-bound). Atomics 196K over 3072 addrs = 64/addr, fine.
__global__ __launch_bounds__(256) void k_xmean(const void* x, char* ws){
    const int flag = *(const int*)(ws + O_FLAG);
    float* xmean = (float*)(ws + O_XMEAN);
    int b = blockIdx.x, d0 = blockIdx.y*128, l0 = blockIdx.z*64;
    int tid = threadIdx.x, dl = tid & 127, lh = tid >> 7;
    float acc = 0.f;
    if (flag){
        const ushort_t* xb = (const ushort_t*)x;
        for (int l = l0 + lh; l < l0 + 64; l += 2)
            acc += bf2f(xb[((long)b*L_ + l)*384 + d0 + dl]);
    } else {
        const float* xf = (const float*)x;
        for (int l = l0 + lh; l < l0 + 64; l += 2)
            acc += xf[((long)b*L_ + l)*384 + d0 + dl];
    }
    __shared__ float s[256];
    s[tid] = acc; __syncthreads();
    if (tid < 128)
        atomicAdd(&xmean[b*384 + d0 + dl], (s[tid] + s[tid+128]) * (1.f/L_));
}

// ---------------- k4: GEMM1  xn @ W_in -> xp | silu(z) ---------
__global__ __launch_bounds__(256) void k_gemm1(char* ws){
    const ushort_t* xn = (const ushort_t*)(ws + O_XN);
    const ushort_t* wT = (const ushort_t*)(ws + O_WINT);
    ushort_t* xp = (ushort_t*)(ws + O_XP);
    ushort_t* zz = (ushort_t*)(ws + O_Z);
    __shared__ ushort_t sA[128*32];
    __shared__ ushort_t sB[128*32];
    int tid = threadIdx.x, w = tid >> 6, l = tid & 63;
    long m0 = (long)blockIdx.x * 128;
    int n0 = blockIdx.y * 128;
    f32x4 acc[4][4] = {};
    int lr = l >> 2, lk = (l & 3) * 8;
    const ushort_t* gA = xn + (m0 + w*16 + lr)*384 + lk;
    const ushort_t* gB = wT + ((long)(n0 + w*16 + lr))*384 + lk;
    ushort_t* lA = &sA[w*16*32];
    ushort_t* lB = &sB[w*16*32];
    int wm = w & 1, wn = w >> 1;
    int arow = wm*64 + (l & 15);
    int brow = wn*64 + (l & 15);
    int koff = (l >> 4) * 8;
    for (int kc = 0; kc < 12; kc++){
        int k0 = kc * 32;
        gload_lds16(gA + k0,           lA);
        gload_lds16(gA + k0 + 64*384,  lA + 64*32);
        gload_lds16(gB + k0,           lB);
        gload_lds16(gB + k0 + 64*384,  lB + 64*32);
        __syncthreads();
        bf16x8 af[4], bfv[4];
        #pragma unroll
        for (int i = 0; i < 4; i++){
            af[i]  = *(const bf16x8*)&sA[(arow + i*16)*32 + koff];
            bfv[i] = *(const bf16x8*)&sB[(brow + i*16)*32 + koff];
        }
        #pragma unroll
        for (int mb = 0; mb < 4; mb++)
            #pragma unroll
            for (int nb = 0; nb < 4; nb++)
                acc[mb][nb] = __builtin_amdgcn_mfma_f32_16x16x32_bf16(af[mb], bfv[nb], acc[mb][nb], 0, 0, 0);
        __syncthreads();
    }
    ushort_t* outp; int nc0; bool isz;
    if (n0 < 768){ outp = xp; nc0 = n0; isz = false; }
    else { outp = zz; nc0 = n0 - 768; isz = true; }
    int rbase = (l >> 4) * 4, cl = l & 15;
    #pragma unroll
    for (int mb = 0; mb < 4; mb++)
        #pragma unroll
        for (int nb = 0; nb < 4; nb++){
            long row = m0 + wm*64 + mb*16 + rbase;
            int col = nc0 + wn*64 + nb*16 + cl;
            #pragma unroll
            for (int r = 0; r < 4; r++){
                float v = acc[mb][nb][r];
                if (isz) v = v * sigm(v);        // fused silu for z
                outp[(row + r)*768 + col] = f2bf(v);
            }
        }
}

// ---------------- k5: causal depthwise conv K=4 + SiLU, vec4 ----------------
// R7: was scalar bf16 (2B/lane) on ~120 MB traffic — G13: hipcc doesn't
// vectorize bf16; scalar ~2x slower. Now 4 d per thread via ushort4
// (8B loads/stores, 1/4 the mem instructions, same bytes). 192 thr cover
// 768 d; grid (1, 512, 8) = 4096 blocks = 16/CU.
__global__ __launch_bounds__(192) void k_conv(char* ws){
    const ushort_t* xp = (const ushort_t*)(ws + O_XP);
    ushort_t* xc = (ushort_t*)(ws + O_XC);
    const float* cw = (const float*)(ws + O_CONVW);
    const float* cb = (const float*)(ws + O_CONVB);
    int d0 = threadIdx.x * 4;
    int t0 = blockIdx.y * 8;
    int b = blockIdx.z;
    long rbase = (long)b * L_;
    f32x4 w0, w1, w2, w3, bias;
    #pragma unroll
    for (int c = 0; c < 4; c++){
        w0[c] = cw[(d0+c)*4+0]; w1[c] = cw[(d0+c)*4+1];
        w2[c] = cw[(d0+c)*4+2]; w3[c] = cw[(d0+c)*4+3];
        bias[c] = cb[d0+c];
    }
    f32x4 xv[11];
    #pragma unroll
    for (int i = 0; i < 11; i++){
        int t = t0 - 3 + i;
        if (t >= 0){
            us4 v = *(const us4*)&xp[(rbase + t)*768 + d0];
            #pragma unroll
            for (int c = 0; c < 4; c++) xv[i][c] = bf2f(v[c]);
        } else {
            xv[i] = f32x4{0.f, 0.f, 0.f, 0.f};
        }
    }
    #pragma unroll
    for (int tt = 0; tt < 8; tt++){
        f32x4 v = bias + xv[tt]*w0 + xv[tt+1]*w1 + xv[tt+2]*w2 + xv[tt+3]*w3;
        us4 o;
        #pragma unroll
        for (int c = 0; c < 4; c++){
            float s = v[c] * sigm(v[c]);
            o[c] = f2bf(s);
        }
        *(us4*)&xc[(rbase + t0 + tt)*768 + d0] = o;
    }
}

// ---------------- k6: xproj  xc @ W_xproj -> x_dbl[32768,56] ----
__global__ __launch_bounds__(256) void k_xproj(char* ws){
    const ushort_t* xc = (const ushort_t*)(ws + O_XC);
    const ushort_t* wT = (const ushort_t*)(ws + O_WXT);
    float* xdbl = (float*)(ws + O_XDBL);
    __shared__ ushort_t sA[128*32];
    __shared__ ushort_t sB[64*32];
    int tid = threadIdx.x, w = tid >> 6, l = tid & 63;
    long m0 = (long)blockIdx.x * 128;
    f32x4 acc[2][4] = {};
    int lr = l >> 2, lk = (l & 3) * 8;
    const ushort_t* gA = xc + (m0 + w*16 + lr)*768 + lk;
    const ushort_t* gB = wT + ((long)(w*16 + lr))*768 + lk;
    ushort_t* lA = &sA[w*16*32];
    ushort_t* lB = &sB[w*16*32];
    int arow0 = w*32 + (l & 15);
    int brow = l & 15;
    int koff = (l >> 4) * 8;
    for (int kc = 0; kc < 24; kc++){
        int k0 = kc * 32;
        gload_lds16(gA + k0,           lA);
        gload_lds16(gA + k0 + 64*768,  lA + 64*32);
        gload_lds16(gB + k0,           lB);
        __syncthreads();
        bf16x8 af[2], bfv[4];
        af[0] = *(const bf16x8*)&sA[arow0*32 + koff];
        af[1] = *(const bf16x8*)&sA[(arow0+16)*32 + koff];
        #pragma unroll
        for (int nb = 0; nb < 4; nb++)
            bfv[nb] = *(const bf16x8*)&sB[(nb*16 + brow)*32 + koff];
        #pragma unroll
        for (int mb = 0; mb < 2; mb++)
            #pragma unroll
            for (int nb = 0; nb < 4; nb++)
                acc[mb][nb] = __builtin_amdgcn_mfma_f32_16x16x32_bf16(af[mb], bfv[nb], acc[mb][nb], 0, 0, 0);
        __syncthreads();
    }
    int rbase = (l >> 4) * 4, cl = l & 15;
    #pragma unroll
    for (int mb = 0; mb < 2; mb++)
        #pragma unroll
        for (int nb = 0; nb < 4; nb++){
            int col = nb*16 + cl;
            if (col < 56){
                long row = m0 + w*32 + mb*16 + rbase;
                #pragma unroll
                for (int r = 0; r < 4; r++)
                    xdbl[(row + r)*56 + col] = acc[mb][nb][r];
            }
        }
}

// ---------------- k7: chunk-parallel selective scan (pass 1) --------------
// v10 (unchanged; issue-bound at ~144us, parked — see R6 note).
__global__ __launch_bounds__(256, 3) void k_scan(char* ws){
    const ushort_t* xc = (const ushort_t*)(ws + O_XC);
    const ushort_t* wz = (const ushort_t*)(ws + O_Z);      // silu(z)
    const float* xdbl = (const float*)(ws + O_XDBL);
    const float* Ag = (const float*)(ws + O_A);            // -exp(A_log)*log2e
    const float* Dsk = (const float*)(ws + O_DSKIP);
    const float* Wdt = (const float*)(ws + O_WDT);
    const float* dtb = (const float*)(ws + O_DTB);
    float* FX = (float*)(ws + O_FX);
    int tid = threadIdx.x;
    int half = tid & 1, p = tid >> 1;          // pair = lanes 2k,2k+1; 128 pairs
    int d = blockIdx.x * 256 + p;              // channel A; channel B = d+128
    int c = blockIdx.y, b = blockIdx.z;
    long row0 = (long)b * L_ + (long)c * CL;

    __shared__ float sXD[CL*56];               // 28 KB: whole chunk's xdbl
    {
        const f32x4* src = (const f32x4*)(xdbl + row0*56);   // 1792 vec4
        f32x4* dst = (f32x4*)sXD;
        #pragma unroll
        for (int i = 0; i < 7; i++) dst[tid + i*256] = src[tid + i*256];
    }

    f32x2 wdtA[6], wdtB[6];
    #pragma unroll
    for (int k = 0; k < 6; k++){
        wdtA[k][0] = Wdt[(half*12 + 2*k    )*768 + d];
        wdtA[k][1] = Wdt[(half*12 + 2*k + 1)*768 + d];
        wdtB[k][0] = Wdt[(half*12 + 2*k    )*768 + d + 128];
        wdtB[k][1] = Wdt[(half*12 + 2*k + 1)*768 + d + 128];
    }
    float dbiasA = half ? 0.f : dtb[d];
    float dbiasB = half ? 0.f : dtb[d + 128];
    f32x2 AvA[4], AvB[4];
    #pragma unroll
    for (int j = 0; j < 4; j++){
        AvA[j][0] = Ag[d*16 + half*8 + 2*j];
        AvA[j][1] = Ag[d*16 + half*8 + 2*j + 1];
        AvB[j][0] = Ag[(d+128)*16 + half*8 + 2*j];
        AvB[j][1] = Ag[(d+128)*16 + half*8 + 2*j + 1];
    }
    float DvA = Dsk[d], DvB = Dsk[d + 128];
    __syncthreads();                           // the only barrier

    f32x2 hA[4], qA[4], GA[4], hB[4], qB[4], GB[4];
    #pragma unroll
    for (int j = 0; j < 4; j++){
        hA[j] = f32x2{0.f,0.f}; GA[j] = f32x2{0.f,0.f}; qA[j] = f32x2{1.f,1.f};
        hB[j] = f32x2{0.f,0.f}; GB[j] = f32x2{0.f,0.f}; qB[j] = f32x2{1.f,1.f};
    }
    f32x2 ysA2 = {0.f,0.f}, ysB2 = {0.f,0.f};
    float sdwA = 0.f, sdwB = 0.f;

    const ushort_t* gx = (half ? wz : xc) + row0*768 + d;   // parity-split stream

    #pragma unroll 4
    for (int t = 0; t < CL; t++){
        ushort_t mA = gx[t*768];
        ushort_t mB = gx[t*768 + 128];
        const float* xd = &sXD[t*56];
        // dt dot for both channels — xd vec4 loads shared
        f32x2 accA = {dbiasA, 0.f}, accB = {dbiasB, 0.f};
        #pragma unroll
        for (int j = 0; j < 3; j++){
            f32x4 v = *(const f32x4*)&xd[half*12 + j*4];
            f32x2 vlo = {v[0], v[1]}, vhi = {v[2], v[3]};
            accA += vlo * wdtA[2*j];  accA += vhi * wdtA[2*j + 1];
            accB += vlo * wdtB[2*j];  accB += vhi * wdtB[2*j + 1];
        }
        float dpA = accA[0] + accA[1], dpB = accB[0] + accB[1];
        float dtA = dpA + __shfl_xor(dpA, 1);
        float dtB = dpB + __shfl_xor(dpB, 1);
        // softplus both
        float eA = __builtin_amdgcn_exp2f(dtA * 1.4426950408889634f);
        float sA_ = 0.69314718055994531f * __builtin_amdgcn_logf(1.f + eA);
        dtA = (dtA > 20.f) ? dtA : sA_;
        float eB = __builtin_amdgcn_exp2f(dtB * 1.4426950408889634f);
        float sB_ = 0.69314718055994531f * __builtin_amdgcn_logf(1.f + eB);
        dtB = (dtB > 20.f) ? dtB : sB_;
        // packed xc/z exchange for both channels in ONE shuffle
        u32 pk = (u32)mA | ((u32)mB << 16);
        u32 other = (u32)__shfl_xor((int)pk, 1);
        ushort_t oA = (ushort_t)(other & 0xffffu), oB = (ushort_t)(other >> 16);
        float xcvA = bf2f(half ? oA : mA);
        float wzvA = bf2f(half ? mA : oA);
        float xcvB = bf2f(half ? oB : mB);
        float wzvB = bf2f(half ? mB : oB);
        float uA = dtA * xcvA, uB = dtB * xcvB;
        f32x2 uA2 = {uA,uA}, uB2 = {uB,uB};
        f32x2 wzA2 = {wzvA,wzvA}, wzB2 = {wzvB,wzvB};
        f32x2 dtA2 = {dtA,dtA}, dtB2 = {dtB,dtB};
        // B/C vec4 loads shared between channels (same t, same s-range)
        f32x4 Bva = *(const f32x4*)&xd[24 + half*8];
        f32x4 Bvb = *(const f32x4*)&xd[28 + half*8];
        f32x4 Cva = *(const f32x4*)&xd[40 + half*8];
        f32x4 Cvb = *(const f32x4*)&xd[44 + half*8];
        #pragma unroll
        for (int j = 0; j < 4; j++){
            f32x2 Bj = (j < 2) ? f32x2{Bva[2*j], Bva[2*j+1]} : f32x2{Bvb[2*j-4], Bvb[2*j-3]};
            f32x2 Cj = (j < 2) ? f32x2{Cva[2*j], Cva[2*j+1]} : f32x2{Cvb[2*j-4], Cvb[2*j-3]};
            // channel A
            f32x2 argA = dtA2 * AvA[j];
            f32x2 dAA;
            dAA[0] = __builtin_amdgcn_exp2f(argA[0]);
            dAA[1] = __builtin_amdgcn_exp2f(argA[1]);
            hA[j] = dAA * hA[j] + uA2 * Bj;
            f32x2 CwA = Cj * wzA2;
            ysA2 += hA[j] * CwA;
            qA[j] = qA[j] * dAA;
            GA[j] += qA[j] * CwA;
            // channel B
            f32x2 argB = dtB2 * AvB[j];
            f32x2 dAB;
            dAB[0] = __builtin_amdgcn_exp2f(argB[0]);
            dAB[1] = __builtin_amdgcn_exp2f(argB[1]);
            hB[j] = dAB * hB[j] + uB2 * Bj;
            f32x2 CwB = Cj * wzB2;
            ysB2 += hB[j] * CwB;
            qB[j] = qB[j] * dAB;
            GB[j] += qB[j] * CwB;
        }
        sdwA += xcvA * wzvA;
        sdwB += xcvB * wzvB;
    }
    float ysA = ysA2[0] + ysA2[1] + (half ? 0.f : DvA * sdwA);
    float ysB = ysB2[0] + ysB2[1] + (half ? 0.f : DvB * sdwB);
    ysA += __shfl_xor(ysA, 1);
    ysB += __shfl_xor(ysB, 1);
    long fbA = ((long)(b*NCHUNK + c)*49)*768 + d;
    long fbB = fbA + 128;
    if (!half){ FX[fbA] = ysA; FX[fbB] = ysB; }
    #pragma unroll
    for (int j = 0; j < 4; j++){
        int sg = half*8 + 2*j;
        FX[fbA + (1+sg)*768]  = hA[j][0];  FX[fbA + (2+sg)*768]  = hA[j][1];
        FX[fbA + (17+sg)*768] = qA[j][0];  FX[fbA + (18+sg)*768] = qA[j][1];
        FX[fbA + (33+sg)*768] = GA[j][0];  FX[fbA + (34+sg)*768] = GA[j][1];
        FX[fbB + (1+sg)*768]  = hB[j][0];  FX[fbB + (2+sg)*768]  = hB[j][1];
        FX[fbB + (17+sg)*768] = qB[j][0];  FX[fbB + (18+sg)*768] = qB[j][1];
        FX[fbB + (33+sg)*768] = GB[j][0];  FX[fbB + (34+sg)*768] = GB[j][1];
    }
}

// ---------------- k8: scan pass 2 — stitch chunks (thread per (b,d,s)) ----
__global__ __launch_bounds__(256) void k_fix(char* ws){
    const float* FX = (const float*)(ws + O_FX);
    float* ymean = (float*)(ws + O_YMEAN);
    int tid = threadIdx.x;
    int dl = tid & 15, s = tid >> 4;
    int d = blockIdx.x * 16 + dl;
    int b = blockIdx.y;
    float Hrun = 0.f, ys = 0.f;
    for (int c = 0; c < NCHUNK; c++){
        long fb = ((long)(b*NCHUNK + c)*49)*768 + d;
        float Gs = FX[fb + (33+s)*768];
        float Hs = FX[fb + (1+s)*768];
        float qs = FX[fb + (17+s)*768];
        ys += Hrun * Gs;
        if (s == 0) ys += FX[fb];
        Hrun = Hs + qs * Hrun;
    }
    __shared__ float sR[256];
    sR[tid] = ys;
    __syncthreads();
    #pragma unroll
    for (int st = 8; st >= 1; st >>= 1){
        if (s < st) sR[tid] += sR[tid + st*16];
        __syncthreads();
    }
    if (s == 0) ymean[b*768 + d] = sR[dl] * (1.f/L_);
}

// ---------------- k9a: sP = xmean + ymean @ Wout  (in-place into xmean) ---
__global__ __launch_bounds__(256) void k_head1a(char* ws){
    const float* ymean = (const float*)(ws + O_YMEAN);
    const float* Wout = (const float*)(ws + O_WOUT);
    float* xmean = (float*)(ws + O_XMEAN);     // becomes sP
    int b = blockIdx.x;
    int d = blockIdx.y*128 + (threadIdx.x >> 1);
    int half = threadIdx.x & 1;
    const float* ym = ymean + b*768 + half*384;
    const float* wo = Wout + (long)half*384*384 + d;
    float acc = 0.f;
    #pragma unroll 8
    for (int i = 0; i < 384; i++)
        acc += ym[i] * wo[i*384];
    acc += __shfl_xor(acc, 1);
    if (!half) xmean[b*384 + d] += acc;
}

// ---------------- k9b: h = sP @ W_fc + b_fc ------------------------------
__global__ __launch_bounds__(256) void k_head1(char* ws){
    const float* sP = (const float*)(ws + O_XMEAN);
    const float* Wfc = (const float*)(ws + O_WFC);
    const float* bfc = (const float*)(ws + O_BFC);
    float* hbuf = (float*)(ws + O_H);
    int b = blockIdx.x, tid = threadIdx.x;
    __shared__ float sPl[384];
    for (int i = tid; i < 384; i += 256) sPl[i] = sP[b*384 + i];
    __syncthreads();
    float v = bfc[tid];
    #pragma unroll 8
    for (int dd = 0; dd < 384; dd++) v += sPl[dd] * Wfc[dd*256 + tid];
    hbuf[b*256 + tid] = v;
}

// ---------------- k10: head part 2: batchnorm + relu + classifier --------
__global__ __launch_bounds__(384) void k_head2(char* ws, void* out){
    const int flag = *(const int*)(ws + O_FLAG);
    const float* hbuf = (const float*)(ws + O_H);
    const float* gam = (const float*)(ws + O_GAM);
    const float* bet = (const float*)(ws + O_BET);
    const float* Wcls = (const float*)(ws + O_WCLS);
    const float* bcls = (const float*)(ws + O_BCLS);
    int tid = threadIdx.x;
    __shared__ float sH[8*256];
    if (tid < 256){
        float hv[8]; float mu = 0.f;
        #pragma unroll
        for (int b = 0; b < 8; b++){ hv[b] = hbuf[b*256 + tid]; mu += hv[b]; }
        mu *= 0.125f;
        float var = 0.f;
        #pragma unroll
        for (int b = 0; b < 8; b++){ float dv = hv[b]-mu; var += dv*dv; }
        var *= 0.125f;
        float rs = rsqrtf(var + 1e-5f);
        #pragma unroll
        for (int b = 0; b < 8; b++){
            float t = (hv[b]-mu)*rs*gam[tid] + bet[tid];
            sH[b*256 + tid] = t > 0.f ? t : 0.f;
        }
    }
    __syncthreads();
    if (tid < 320){
        int b = tid / 40, c = tid % 40;
        float acc = bcls[c];
        for (int j = 0; j < 256; j++) acc += sH[b*256 + j] * Wcls[j*40 + c];
        if (flag) ((ushort_t*)out)[b*40 + c] = f2bf(acc);
        else      ((float*)out)[b*40 + c] = acc;
    }
}

// ---------------- launch ----------------
extern "C" void kernel_launch(void* const* d_in, const int* in_sizes, int n_in,
                              void* d_out, int out_size, void* d_ws, size_t ws_size,
                              hipStream_t stream){
    (void)in_sizes; (void)n_in; (void)out_size; (void)ws_size;
    char* ws = (char*)d_ws;
    Ptrs ps;
    for (int i = 0; i < 17; i++) ps.p[i] = d_in[i];

    k_detect<<<1, 256, 0, stream>>>(d_in[0], ws);
    k_prep<<<(unsigned)((N_PREP + 255) / 256), 256, 0, stream>>>(ps, ws);
    k_rmsnorm<<<ML_/4, 256, 0, stream>>>(d_in[0], ws);
    k_xmean<<<dim3(8, 3, 64), 256, 0, stream>>>(d_in[0], ws);
    k_gemm1<<<dim3(ML_/128, 12), 256, 0, stream>>>(ws);
    k_conv<<<dim3(1, L_/8, B_), 192, 0, stream>>>(ws);
    k_xproj<<<ML_/128, 256, 0, stream>>>(ws);
    k_scan<<<dim3(3, NCHUNK, B_), 256, 0, stream>>>(ws);
    k_fix<<<dim3(48, B_), 256, 0, stream>>>(ws);
    k_head1a<<<dim3(8, 3), 256, 0, stream>>>(ws);
    k_head1<<<B_, 256, 0, stream>>>(ws);
    k_head2<<<1, 384, 0, stream>>>(ws, d_out);
}

// Round 9
// 450.492 us; speedup vs baseline: 4.9810x; 1.0069x over previous
//
#include <hip/hip_runtime.h>

typedef unsigned short ushort_t;
typedef unsigned int u32;
typedef float f32x4 __attribute__((ext_vector_type(4)));
typedef float f32x2 __attribute__((ext_vector_type(2)));
typedef __bf16 bf16x8 __attribute__((ext_vector_type(8)));
typedef unsigned short us4 __attribute__((ext_vector_type(4)));

#define B_ 8
#define L_ 4096
#define D_ 384
#define DI_ 768
#define S_ 16
#define NC_ 40
#define ML_ (B_*L_)   // 32768 rows
#define NCHUNK 32
#define CL 128        // chunk length (L_/NCHUNK)

// ---------------- workspace layout (bytes) ----------------
// ~154 MB total. Aliasing:
//   XN lives in XC region (dead after gemm1, before conv writes XC);
//   XDBL lives at start of XP region (XP dead after conv);
//   FX (chunk summaries, 38.5 MB) lives in XP region after XDBL.
constexpr size_t au(size_t x){ return (x + 255) & ~size_t(255); }
constexpr size_t O_FLAG = 0;                                   // int
constexpr size_t O_LNW  = 256;                                 // 384 f32
constexpr size_t O_CONVW= au(O_LNW  + 384*4);                  // 3072 f32
constexpr size_t O_CONVB= au(O_CONVW+ 3072*4);                 // 768 f32
constexpr size_t O_WDT  = au(O_CONVB+ 768*4);                  // 18432 f32
constexpr size_t O_DTB  = au(O_WDT  + 18432*4);                // 768 f32
constexpr size_t O_A    = au(O_DTB  + 768*4);                  // 12288 f32 (A = -exp(A_log)*log2e)
constexpr size_t O_DSKIP= au(O_A    + 12288*4);                // 768 f32
constexpr size_t O_WOUT = au(O_DSKIP+ 768*4);                  // 294912 f32
constexpr size_t O_WFC  = au(O_WOUT + 294912*4);               // 98304 f32
constexpr size_t O_BFC  = au(O_WFC  + 98304*4);                // 256 f32
constexpr size_t O_GAM  = au(O_BFC  + 256*4);
constexpr size_t O_BET  = au(O_GAM  + 256*4);
constexpr size_t O_WCLS = au(O_BET  + 256*4);                  // 10240 f32
constexpr size_t O_BCLS = au(O_WCLS + 10240*4);                // 40 f32
constexpr size_t O_XMEAN= au(O_BCLS + 40*4);                   // 8*384 f32 (atomic acc; later sP in-place)
constexpr size_t O_YMEAN= au(O_XMEAN+ 3072*4);                 // 8*768 f32
constexpr size_t O_H    = au(O_YMEAN+ 6144*4);                 // 8*256 f32
constexpr size_t O_WINT = au(O_H    + 2048*4);                 // W_in^T  [1536][384] bf16
constexpr size_t O_WXT  = au(O_WINT + (size_t)589824*2);       // W_xproj^T padded [64][768] bf16
constexpr size_t O_XP   = au(O_WXT  + (size_t)49152*2);        // [32768][768] bf16
constexpr size_t O_XDBL = O_XP;                                // alias: [32768][56] f32 (after conv)
constexpr size_t O_FX   = au(O_XDBL + (size_t)ML_*56*4);       // [b][c][49][768] f32 chunk summaries
constexpr size_t FX_SZ  = (size_t)B_*NCHUNK*49*768*4;          // 38.5 MB
constexpr size_t O_Z    = au(O_XP   + (size_t)ML_*768*2);      // [32768][768] bf16 (holds silu(z))
constexpr size_t O_XCU  = au(O_Z    + (size_t)ML_*768*2);      // union region, 50.3 MB
constexpr size_t O_XN   = O_XCU;                               // [32768][384] bf16 (dead after gemm1)
constexpr size_t O_XC   = O_XCU;                               // [32768][768] bf16
constexpr size_t WS_NEED= O_XCU + (size_t)ML_*768*2;           // ~154 MB
static_assert(O_FX + FX_SZ <= O_Z, "FX must fit in dead XP tail");

// ---------------- helpers ----------------
__device__ inline float bf2f(ushort_t u){ return __uint_as_float(((u32)u) << 16); }
__device__ inline ushort_t f2bf(float f){
    u32 x = __float_as_uint(f);
    u32 r = (x + 0x7fffu + ((x >> 16) & 1u)) >> 16;   // RNE
    return (ushort_t)r;
}
__device__ inline float ldf(const void* p, long i, int flag){
    return flag ? bf2f(((const ushort_t*)p)[i]) : ((const float*)p)[i];
}
__device__ inline ushort_t ldbf(const void* p, long i, int flag){
    return flag ? ((const ushort_t*)p)[i] : f2bf(((const float*)p)[i]);
}
__device__ inline float sigm(float v){ return 1.f / (1.f + __expf(-v)); }

__device__ inline void gload_lds16(const void* g, void* l){
    __builtin_amdgcn_global_load_lds(
        (const __attribute__((address_space(1))) u32*)g,
        (__attribute__((address_space(3))) u32*)l, 16, 0, 0);
}

struct Ptrs { const void* p[17]; };

// ---------------- k0: dtype detect ----------------
__global__ void k_detect(const void* x, char* ws){
    __shared__ float s[256];
    int tid = threadIdx.x;
    s[tid] = fabsf(bf2f(((const ushort_t*)x)[tid]));
    __syncthreads();
    for (int st = 128; st > 0; st >>= 1){
        if (tid < st) s[tid] = fmaxf(s[tid], s[tid + st]);
        __syncthreads();
    }
    if (tid == 0) *(int*)(ws + O_FLAG) = (s[0] < 1e4f) ? 1 : 0;
}

// ---------------- k1: weight prep ----------------
#define N_PREP 1082792L
__global__ __launch_bounds__(256) void k_prep(Ptrs ps, char* ws){
    const int flag = *(const int*)(ws + O_FLAG);
    long o = (long)blockIdx.x * 256 + threadIdx.x;
    if (o < 384){ ((float*)(ws+O_LNW))[o]  = ldf(ps.p[1],o,flag); return; }  o -= 384;
    if (o < 3072){ ((float*)(ws+O_CONVW))[o]= ldf(ps.p[3],o,flag); return; } o -= 3072;
    if (o < 768){ ((float*)(ws+O_CONVB))[o]= ldf(ps.p[4],o,flag); return; }  o -= 768;
    if (o < 18432){ ((float*)(ws+O_WDT))[o]= ldf(ps.p[6],o,flag); return; }  o -= 18432;
    if (o < 768){ ((float*)(ws+O_DTB))[o]  = ldf(ps.p[7],o,flag); return; }  o -= 768;
    if (o < 768){ ((float*)(ws+O_DSKIP))[o]= ldf(ps.p[9],o,flag); return; }  o -= 768;
    if (o < 294912){ ((float*)(ws+O_WOUT))[o]= ldf(ps.p[10],o,flag); return; } o -= 294912;
    if (o < 98304){ ((float*)(ws+O_WFC))[o]= ldf(ps.p[11],o,flag); return; } o -= 98304;
    if (o < 256){ ((float*)(ws+O_BFC))[o]  = ldf(ps.p[12],o,flag); return; } o -= 256;
    if (o < 256){ ((float*)(ws+O_GAM))[o]  = ldf(ps.p[13],o,flag); return; } o -= 256;
    if (o < 256){ ((float*)(ws+O_BET))[o]  = ldf(ps.p[14],o,flag); return; } o -= 256;
    if (o < 10240){ ((float*)(ws+O_WCLS))[o]= ldf(ps.p[15],o,flag); return; } o -= 10240;
    if (o < 40){ ((float*)(ws+O_BCLS))[o]  = ldf(ps.p[16],o,flag); return; } o -= 40;
    // A = -exp(A_log) * log2(e)   (scan uses exp2)
    if (o < 12288){ ((float*)(ws+O_A))[o]  = -__expf(ldf(ps.p[8],o,flag)) * 1.4426950408889634f; return; } o -= 12288;
    if (o < 589824){                     // W_in [384,1536] -> WinT [1536][384]
        long n = o / 384, k = o % 384;
        ((ushort_t*)(ws+O_WINT))[o] = ldbf(ps.p[2], k*1536 + n, flag); return;
    } o -= 589824;
    if (o < 49152){                      // W_xproj [768,56] -> WxT [64][768], zero-pad n>=56
        long n = o / 768, k = o % 768;
        ((ushort_t*)(ws+O_WXT))[o] = (n < 56) ? ldbf(ps.p[5], k*56 + n, flag) : (ushort_t)0;
        return;
    } o -= 49152;
    if (o < 3072){ ((float*)(ws+O_XMEAN))[o] = 0.f; return; }
}

// ---------------- k2: fused RMSNorm + xmean ----------------
// R8: rmsnorm and xmean both streamed the same 50 MB input. Fused: 16 rows
// per block (4 waves x 4 rows serial), raw-x accumulated in registers,
// 4-way LDS reduce, 1 atomicAdd per (block,d): 2048x384 = 786K atomics,
// 256 per address. Saves one full input read + one launch.
__global__ __launch_bounds__(256) void k_rmsxm(const void* x, char* ws){
    const int flag = *(const int*)(ws + O_FLAG);
    const float* lnw = (const float*)(ws + O_LNW);
    ushort_t* xn = (ushort_t*)(ws + O_XN);
    float* xmean = (float*)(ws + O_XMEAN);
    int tid = threadIdx.x;
    int lane = tid & 63, w = tid >> 6;
    long row0 = (long)blockIdx.x * 16 + w * 4;
    int b = blockIdx.x >> 8;                   // 256 blocks per batch
    float lw[6];
    #pragma unroll
    for (int k = 0; k < 6; k++) lw[k] = lnw[lane + k*64];
    float xacc[6] = {0.f,0.f,0.f,0.f,0.f,0.f};
    for (int i = 0; i < 4; i++){
        long row = row0 + i;
        float v[6];
        if (flag){
            const ushort_t* xb = (const ushort_t*)x + row*384;
            #pragma unroll
            for (int k = 0; k < 6; k++) v[k] = bf2f(xb[lane + k*64]);
        } else {
            const float* xf = (const float*)x + row*384;
            #pragma unroll
            for (int k = 0; k < 6; k++) v[k] = xf[lane + k*64];
        }
        float ss = 0.f;
        #pragma unroll
        for (int k = 0; k < 6; k++) ss += v[k]*v[k];
        #pragma unroll
        for (int m = 1; m < 64; m <<= 1) ss += __shfl_xor(ss, m);
        float scale = rsqrtf(ss * (1.f/384.f) + 1e-5f);
        #pragma unroll
        for (int k = 0; k < 6; k++){
            xn[row*384 + lane + k*64] = f2bf(v[k] * scale * lw[k]);
            xacc[k] += v[k];
        }
    }
    __shared__ float part[4][384];
    #pragma unroll
    for (int k = 0; k < 6; k++) part[w][lane + k*64] = xacc[k];
    __syncthreads();
    for (int d = tid; d < 384; d += 256){
        float s = part[0][d] + part[1][d] + part[2][d] + part[3][d];
        atomicAdd(&xmean[b*384 + d], s * (1.f/L_));
    }
}

// ---------------- k4: GEMM1  xn @ W_in -> xp | silu(z) ---------
// R8: operand-swapped MFMA (mfma(bfv, af)) -> D row index = n (b-operand,
// reg gives 4 CONSECUTIVE n), col = m. Epilogue: 64 scalar ushort stores
// -> 16 x us4 (8B) stores. Same 32B-segment coalescing, 4x fewer store
// + address instructions. At K=384 (12 k-iters) the epilogue was a large
// fraction of block time.
__global__ __launch_bounds__(256) void k_gemm1(char* ws){
    const ushort_t* xn = (const ushort_t*)(ws + O_XN);
    const ushort_t* wT = (const ushort_t*)(ws + O_WINT);
    ushort_t* xp = (ushort_t*)(ws + O_XP);
    ushort_t* zz = (ushort_t*)(ws + O_Z);
    __shared__ ushort_t sA[128*32];
    __shared__ ushort_t sB[128*32];
    int tid = threadIdx.x, w = tid >> 6, l = tid & 63;
    long m0 = (long)blockIdx.x * 128;
    int n0 = blockIdx.y * 128;
    f32x4 acc[4][4] = {};
    int lr = l >> 2, lk = (l & 3) * 8;
    const ushort_t* gA = xn + (m0 + w*16 + lr)*384 + lk;
    const ushort_t* gB = wT + ((long)(n0 + w*16 + lr))*384 + lk;
    ushort_t* lA = &sA[w*16*32];
    ushort_t* lB = &sB[w*16*32];
    int wm = w & 1, wn = w >> 1;
    int arow = wm*64 + (l & 15);
    int brow = wn*64 + (l & 15);
    int koff = (l >> 4) * 8;
    for (int kc = 0; kc < 12; kc++){
        int k0 = kc * 32;
        gload_lds16(gA + k0,           lA);
        gload_lds16(gA + k0 + 64*384,  lA + 64*32);
        gload_lds16(gB + k0,           lB);
        gload_lds16(gB + k0 + 64*384,  lB + 64*32);
        __syncthreads();
        bf16x8 af[4], bfv[4];
        #pragma unroll
        for (int i = 0; i < 4; i++){
            af[i]  = *(const bf16x8*)&sA[(arow + i*16)*32 + koff];
            bfv[i] = *(const bf16x8*)&sB[(brow + i*16)*32 + koff];
        }
        #pragma unroll
        for (int mb = 0; mb < 4; mb++)
            #pragma unroll
            for (int nb = 0; nb < 4; nb++)
                acc[mb][nb] = __builtin_amdgcn_mfma_f32_16x16x32_bf16(bfv[nb], af[mb], acc[mb][nb], 0, 0, 0);
        __syncthreads();
    }
    ushort_t* outp; int nc0; bool isz;
    if (n0 < 768){ outp = xp; nc0 = n0; isz = false; }
    else { outp = zz; nc0 = n0 - 768; isz = true; }
    int cl = l & 15, rb4 = (l >> 4) * 4;
    #pragma unroll
    for (int mb = 0; mb < 4; mb++)
        #pragma unroll
        for (int nb = 0; nb < 4; nb++){
            long row = m0 + wm*64 + mb*16 + cl;
            int col = nc0 + wn*64 + nb*16 + rb4;
            us4 o;
            #pragma unroll
            for (int r = 0; r < 4; r++){
                float v = acc[mb][nb][r];
                if (isz) v = v * sigm(v);        // fused silu for z
                o[r] = f2bf(v);
            }
            *(us4*)&outp[row*768 + col] = o;
        }
}

// ---------------- k5: causal depthwise conv K=4 + SiLU, vec4 ----------------
__global__ __launch_bounds__(192) void k_conv(char* ws){
    const ushort_t* xp = (const ushort_t*)(ws + O_XP);
    ushort_t* xc = (ushort_t*)(ws + O_XC);
    const float* cw = (const float*)(ws + O_CONVW);
    const float* cb = (const float*)(ws + O_CONVB);
    int d0 = threadIdx.x * 4;
    int t0 = blockIdx.y * 8;
    int b = blockIdx.z;
    long rbase = (long)b * L_;
    f32x4 w0, w1, w2, w3, bias;
    #pragma unroll
    for (int c = 0; c < 4; c++){
        w0[c] = cw[(d0+c)*4+0]; w1[c] = cw[(d0+c)*4+1];
        w2[c] = cw[(d0+c)*4+2]; w3[c] = cw[(d0+c)*4+3];
        bias[c] = cb[d0+c];
    }
    f32x4 xv[11];
    #pragma unroll
    for (int i = 0; i < 11; i++){
        int t = t0 - 3 + i;
        if (t >= 0){
            us4 v = *(const us4*)&xp[(rbase + t)*768 + d0];
            #pragma unroll
            for (int c = 0; c < 4; c++) xv[i][c] = bf2f(v[c]);
        } else {
            xv[i] = f32x4{0.f, 0.f, 0.f, 0.f};
        }
    }
    #pragma unroll
    for (int tt = 0; tt < 8; tt++){
        f32x4 v = bias + xv[tt]*w0 + xv[tt+1]*w1 + xv[tt+2]*w2 + xv[tt+3]*w3;
        us4 o;
        #pragma unroll
        for (int c = 0; c < 4; c++){
            float s = v[c] * sigm(v[c]);
            o[c] = f2bf(s);
        }
        *(us4*)&xc[(rbase + t0 + tt)*768 + d0] = o;
    }
}

// ---------------- k6: xproj  xc @ W_xproj -> x_dbl[32768,56] ----
// R8: operand-swapped MFMA -> 4 consecutive n per thread; guarded scalar
// f32 stores (32) -> aligned f32x4 stores (<=8, nbase<56 guard).
__global__ __launch_bounds__(256) void k_xproj(char* ws){
    const ushort_t* xc = (const ushort_t*)(ws + O_XC);
    const ushort_t* wT = (const ushort_t*)(ws + O_WXT);
    float* xdbl = (float*)(ws + O_XDBL);
    __shared__ ushort_t sA[128*32];
    __shared__ ushort_t sB[64*32];
    int tid = threadIdx.x, w = tid >> 6, l = tid & 63;
    long m0 = (long)blockIdx.x * 128;
    f32x4 acc[2][4] = {};
    int lr = l >> 2, lk = (l & 3) * 8;
    const ushort_t* gA = xc + (m0 + w*16 + lr)*768 + lk;
    const ushort_t* gB = wT + ((long)(w*16 + lr))*768 + lk;
    ushort_t* lA = &sA[w*16*32];
    ushort_t* lB = &sB[w*16*32];
    int arow0 = w*32 + (l & 15);
    int brow = l & 15;
    int koff = (l >> 4) * 8;
    for (int kc = 0; kc < 24; kc++){
        int k0 = kc * 32;
        gload_lds16(gA + k0,           lA);
        gload_lds16(gA + k0 + 64*768,  lA + 64*32);
        gload_lds16(gB + k0,           lB);
        __syncthreads();
        bf16x8 af[2], bfv[4];
        af[0] = *(const bf16x8*)&sA[arow0*32 + koff];
        af[1] = *(const bf16x8*)&sA[(arow0+16)*32 + koff];
        #pragma unroll
        for (int nb = 0; nb < 4; nb++)
            bfv[nb] = *(const bf16x8*)&sB[(nb*16 + brow)*32 + koff];
        #pragma unroll
        for (int mb = 0; mb < 2; mb++)
            #pragma unroll
            for (int nb = 0; nb < 4; nb++)
                acc[mb][nb] = __builtin_amdgcn_mfma_f32_16x16x32_bf16(bfv[nb], af[mb], acc[mb][nb], 0, 0, 0);
        __syncthreads();
    }
    int cl = l & 15, rb4 = (l >> 4) * 4;
    #pragma unroll
    for (int mb = 0; mb < 2; mb++)
        #pragma unroll
        for (int nb = 0; nb < 4; nb++){
            int nbase = nb*16 + rb4;
            if (nbase < 56){
                long row = m0 + w*32 + mb*16 + cl;
                *(f32x4*)&xdbl[row*56 + nbase] = acc[mb][nb];
            }
        }
}

// ---------------- k7: chunk-parallel selective scan (pass 1) --------------
// v10 (unchanged; issue-bound at ~144us, parked — see R6 note).
__global__ __launch_bounds__(256, 3) void k_scan(char* ws){
    const ushort_t* xc = (const ushort_t*)(ws + O_XC);
    const ushort_t* wz = (const ushort_t*)(ws + O_Z);      // silu(z)
    const float* xdbl = (const float*)(ws + O_XDBL);
    const float* Ag = (const float*)(ws + O_A);            // -exp(A_log)*log2e
    const float* Dsk = (const float*)(ws + O_DSKIP);
    const float* Wdt = (const float*)(ws + O_WDT);
    const float* dtb = (const float*)(ws + O_DTB);
    float* FX = (float*)(ws + O_FX);
    int tid = threadIdx.x;
    int half = tid & 1, p = tid >> 1;          // pair = lanes 2k,2k+1; 128 pairs
    int d = blockIdx.x * 256 + p;              // channel A; channel B = d+128
    int c = blockIdx.y, b = blockIdx.z;
    long row0 = (long)b * L_ + (long)c * CL;

    __shared__ float sXD[CL*56];               // 28 KB: whole chunk's xdbl
    {
        const f32x4* src = (const f32x4*)(xdbl + row0*56);   // 1792 vec4
        f32x4* dst = (f32x4*)sXD;
        #pragma unroll
        for (int i = 0; i < 7; i++) dst[tid + i*256] = src[tid + i*256];
    }

    f32x2 wdtA[6], wdtB[6];
    #pragma unroll
    for (int k = 0; k < 6; k++){
        wdtA[k][0] = Wdt[(half*12 + 2*k    )*768 + d];
        wdtA[k][1] = Wdt[(half*12 + 2*k + 1)*768 + d];
        wdtB[k][0] = Wdt[(half*12 + 2*k    )*768 + d + 128];
        wdtB[k][1] = Wdt[(half*12 + 2*k + 1)*768 + d + 128];
    }
    float dbiasA = half ? 0.f : dtb[d];
    float dbiasB = half ? 0.f : dtb[d + 128];
    f32x2 AvA[4], AvB[4];
    #pragma unroll
    for (int j = 0; j < 4; j++){
        AvA[j][0] = Ag[d*16 + half*8 + 2*j];
        AvA[j][1] = Ag[d*16 + half*8 + 2*j + 1];
        AvB[j][0] = Ag[(d+128)*16 + half*8 + 2*j];
        AvB[j][1] = Ag[(d+128)*16 + half*8 + 2*j + 1];
    }
    float DvA = Dsk[d], DvB = Dsk[d + 128];
    __syncthreads();                           // the only barrier

    f32x2 hA[4], qA[4], GA[4], hB[4], qB[4], GB[4];
    #pragma unroll
    for (int j = 0; j < 4; j++){
        hA[j] = f32x2{0.f,0.f}; GA[j] = f32x2{0.f,0.f}; qA[j] = f32x2{1.f,1.f};
        hB[j] = f32x2{0.f,0.f}; GB[j] = f32x2{0.f,0.f}; qB[j] = f32x2{1.f,1.f};
    }
    f32x2 ysA2 = {0.f,0.f}, ysB2 = {0.f,0.f};
    float sdwA = 0.f, sdwB = 0.f;

    const ushort_t* gx = (half ? wz : xc) + row0*768 + d;   // parity-split stream

    #pragma unroll 4
    for (int t = 0; t < CL; t++){
        ushort_t mA = gx[t*768];
        ushort_t mB = gx[t*768 + 128];
        const float* xd = &sXD[t*56];
        // dt dot for both channels — xd vec4 loads shared
        f32x2 accA = {dbiasA, 0.f}, accB = {dbiasB, 0.f};
        #pragma unroll
        for (int j = 0; j < 3; j++){
            f32x4 v = *(const f32x4*)&xd[half*12 + j*4];
            f32x2 vlo = {v[0], v[1]}, vhi = {v[2], v[3]};
            accA += vlo * wdtA[2*j];  accA += vhi * wdtA[2*j + 1];
            accB += vlo * wdtB[2*j];  accB += vhi * wdtB[2*j + 1];
        }
        float dpA = accA[0] + accA[1], dpB = accB[0] + accB[1];
        float dtA = dpA + __shfl_xor(dpA, 1);
        float dtB = dpB + __shfl_xor(dpB, 1);
        // softplus both
        float eA = __builtin_amdgcn_exp2f(dtA * 1.4426950408889634f);
        float sA_ = 0.69314718055994531f * __builtin_amdgcn_logf(1.f + eA);
        dtA = (dtA > 20.f) ? dtA : sA_;
        float eB = __builtin_amdgcn_exp2f(dtB * 1.4426950408889634f);
        float sB_ = 0.69314718055994531f * __builtin_amdgcn_logf(1.f + eB);
        dtB = (dtB > 20.f) ? dtB : sB_;
        // packed xc/z exchange for both channels in ONE shuffle
        u32 pk = (u32)mA | ((u32)mB << 16);
        u32 other = (u32)__shfl_xor((int)pk, 1);
        ushort_t oA = (ushort_t)(other & 0xffffu), oB = (ushort_t)(other >> 16);
        float xcvA = bf2f(half ? oA : mA);
        float wzvA = bf2f(half ? mA : oA);
        float xcvB = bf2f(half ? oB : mB);
        float wzvB = bf2f(half ? mB : oB);
        float uA = dtA * xcvA, uB = dtB * xcvB;
        f32x2 uA2 = {uA,uA}, uB2 = {uB,uB};
        f32x2 wzA2 = {wzvA,wzvA}, wzB2 = {wzvB,wzvB};
        f32x2 dtA2 = {dtA,dtA}, dtB2 = {dtB,dtB};
        // B/C vec4 loads shared between channels (same t, same s-range)
        f32x4 Bva = *(const f32x4*)&xd[24 + half*8];
        f32x4 Bvb = *(const f32x4*)&xd[28 + half*8];
        f32x4 Cva = *(const f32x4*)&xd[40 + half*8];
        f32x4 Cvb = *(const f32x4*)&xd[44 + half*8];
        #pragma unroll
        for (int j = 0; j < 4; j++){
            f32x2 Bj = (j < 2) ? f32x2{Bva[2*j], Bva[2*j+1]} : f32x2{Bvb[2*j-4], Bvb[2*j-3]};
            f32x2 Cj = (j < 2) ? f32x2{Cva[2*j], Cva[2*j+1]} : f32x2{Cvb[2*j-4], Cvb[2*j-3]};
            // channel A
            f32x2 argA = dtA2 * AvA[j];
            f32x2 dAA;
            dAA[0] = __builtin_amdgcn_exp2f(argA[0]);
            dAA[1] = __builtin_amdgcn_exp2f(argA[1]);
            hA[j] = dAA * hA[j] + uA2 * Bj;
            f32x2 CwA = Cj * wzA2;
            ysA2 += hA[j] * CwA;
            qA[j] = qA[j] * dAA;
            GA[j] += qA[j] * CwA;
            // channel B
            f32x2 argB = dtB2 * AvB[j];
            f32x2 dAB;
            dAB[0] = __builtin_amdgcn_exp2f(argB[0]);
            dAB[1] = __builtin_amdgcn_exp2f(argB[1]);
            hB[j] = dAB * hB[j] + uB2 * Bj;
            f32x2 CwB = Cj * wzB2;
            ysB2 += hB[j] * CwB;
            qB[j] = qB[j] * dAB;
            GB[j] += qB[j] * CwB;
        }
        sdwA += xcvA * wzvA;
        sdwB += xcvB * wzvB;
    }
    float ysA = ysA2[0] + ysA2[1] + (half ? 0.f : DvA * sdwA);
    float ysB = ysB2[0] + ysB2[1] + (half ? 0.f : DvB * sdwB);
    ysA += __shfl_xor(ysA, 1);
    ysB += __shfl_xor(ysB, 1);
    long fbA = ((long)(b*NCHUNK + c)*49)*768 + d;
    long fbB = fbA + 128;
    if (!half){ FX[fbA] = ysA; FX[fbB] = ysB; }
    #pragma unroll
    for (int j = 0; j < 4; j++){
        int sg = half*8 + 2*j;
        FX[fbA + (1+sg)*768]  = hA[j][0];  FX[fbA + (2+sg)*768]  = hA[j][1];
        FX[fbA + (17+sg)*768] = qA[j][0];  FX[fbA + (18+sg)*768] = qA[j][1];
        FX[fbA + (33+sg)*768] = GA[j][0];  FX[fbA + (34+sg)*768] = GA[j][1];
        FX[fbB + (1+sg)*768]  = hB[j][0];  FX[fbB + (2+sg)*768]  = hB[j][1];
        FX[fbB + (17+sg)*768] = qB[j][0];  FX[fbB + (18+sg)*768] = qB[j][1];
        FX[fbB + (33+sg)*768] = GB[j][0];  FX[fbB + (34+sg)*768] = GB[j][1];
    }
}

// ---------------- k8: scan pass 2 — stitch chunks (thread per (b,d,s)) ----
__global__ __launch_bounds__(256) void k_fix(char* ws){
    const float* FX = (const float*)(ws + O_FX);
    float* ymean = (float*)(ws + O_YMEAN);
    int tid = threadIdx.x;
    int dl = tid & 15, s = tid >> 4;
    int d = blockIdx.x * 16 + dl;
    int b = blockIdx.y;
    float Hrun = 0.f, ys = 0.f;
    for (int c = 0; c < NCHUNK; c++){
        long fb = ((long)(b*NCHUNK + c)*49)*768 + d;
        float Gs = FX[fb + (33+s)*768];
        float Hs = FX[fb + (1+s)*768];
        float qs = FX[fb + (17+s)*768];
        ys += Hrun * Gs;
        if (s == 0) ys += FX[fb];
        Hrun = Hs + qs * Hrun;
    }
    __shared__ float sR[256];
    sR[tid] = ys;
    __syncthreads();
    #pragma unroll
    for (int st = 8; st >= 1; st >>= 1){
        if (s < st) sR[tid] += sR[tid + st*16];
        __syncthreads();
    }
    if (s == 0) ymean[b*768 + d] = sR[dl] * (1.f/L_);
}

// ---------------- k9a: sP = xmean + ymean @ Wout  (in-place into xmean) ---
__global__ __launch_bounds__(256) void k_head1a(char* ws){
    const float* ymean = (const float*)(ws + O_YMEAN);
    const float* Wout = (const float*)(ws + O_WOUT);
    float* xmean = (float*)(ws + O_XMEAN);     // becomes sP
    int b = blockIdx.x;
    int d = blockIdx.y*128 + (threadIdx.x >> 1);
    int half = threadIdx.x & 1;
    const float* ym = ymean + b*768 + half*384;
    const float* wo = Wout + (long)half*384*384 + d;
    float acc = 0.f;
    #pragma unroll 8
    for (int i = 0; i < 384; i++)
        acc += ym[i] * wo[i*384];
    acc += __shfl_xor(acc, 1);
    if (!half) xmean[b*384 + d] += acc;
}

// ---------------- k9b: h = sP @ W_fc + b_fc ------------------------------
__global__ __launch_bounds__(256) void k_head1(char* ws){
    const float* sP = (const float*)(ws + O_XMEAN);
    const float* Wfc = (const float*)(ws + O_WFC);
    const float* bfc = (const float*)(ws + O_BFC);
    float* hbuf = (float*)(ws + O_H);
    int b = blockIdx.x, tid = threadIdx.x;
    __shared__ float sPl[384];
    for (int i = tid; i < 384; i += 256) sPl[i] = sP[b*384 + i];
    __syncthreads();
    float v = bfc[tid];
    #pragma unroll 8
    for (int dd = 0; dd < 384; dd++) v += sPl[dd] * Wfc[dd*256 + tid];
    hbuf[b*256 + tid] = v;
}

// ---------------- k10: head part 2: batchnorm + relu + classifier --------
__global__ __launch_bounds__(384) void k_head2(char* ws, void* out){
    const int flag = *(const int*)(ws + O_FLAG);
    const float* hbuf = (const float*)(ws + O_H);
    const float* gam = (const float*)(ws + O_GAM);
    const float* bet = (const float*)(ws + O_BET);
    const float* Wcls = (const float*)(ws + O_WCLS);
    const float* bcls = (const float*)(ws + O_BCLS);
    int tid = threadIdx.x;
    __shared__ float sH[8*256];
    if (tid < 256){
        float hv[8]; float mu = 0.f;
        #pragma unroll
        for (int b = 0; b < 8; b++){ hv[b] = hbuf[b*256 + tid]; mu += hv[b]; }
        mu *= 0.125f;
        float var = 0.f;
        #pragma unroll
        for (int b = 0; b < 8; b++){ float dv = hv[b]-mu; var += dv*dv; }
        var *= 0.125f;
        float rs = rsqrtf(var + 1e-5f);
        #pragma unroll
        for (int b = 0; b < 8; b++){
            float t = (hv[b]-mu)*rs*gam[tid] + bet[tid];
            sH[b*256 + tid] = t > 0.f ? t : 0.f;
        }
    }
    __syncthreads();
    if (tid < 320){
        int b = tid / 40, c = tid % 40;
        float acc = bcls[c];
        for (int j = 0; j < 256; j++) acc += sH[b*256 + j] * Wcls[j*40 + c];
        if (flag) ((ushort_t*)out)[b*40 + c] = f2bf(acc);
        else      ((float*)out)[b*40 + c] = acc;
    }
}

// ---------------- launch ----------------
extern "C" void kernel_launch(void* const* d_in, const int* in_sizes, int n_in,
                              void* d_out, int out_size, void* d_ws, size_t ws_size,
                              hipStream_t stream){
    (void)in_sizes; (void)n_in; (void)out_size; (void)ws_size;
    char* ws = (char*)d_ws;
    Ptrs ps;
    for (int i = 0; i < 17; i++) ps.p[i] = d_in[i];

    k_detect<<<1, 256, 0, stream>>>(d_in[0], ws);
    k_prep<<<(unsigned)((N_PREP + 255) / 256), 256, 0, stream>>>(ps, ws);
    k_rmsxm<<<ML_/16, 256, 0, stream>>>(d_in[0], ws);
    k_gemm1<<<dim3(ML_/128, 12), 256, 0, stream>>>(ws);
    k_conv<<<dim3(1, L_/8, B_), 192, 0, stream>>>(ws);
    k_xproj<<<ML_/128, 256, 0, stream>>>(ws);
    k_scan<<<dim3(3, NCHUNK, B_), 256, 0, stream>>>(ws);
    k_fix<<<dim3(48, B_), 256, 0, stream>>>(ws);
    k_head1a<<<dim3(8, 3), 256, 0, stream>>>(ws);
    k_head1<<<B_, 256, 0, stream>>>(ws);
    k_head2<<<1, 384, 0, stream>>>(ws, d_out);
}

// Round 10
// 449.241 us; speedup vs baseline: 4.9949x; 1.0028x over previous
//
#include <hip/hip_runtime.h>

typedef unsigned short ushort_t;
typedef unsigned int u32;
typedef float f32x4 __attribute__((ext_vector_type(4)));
typedef float f32x2 __attribute__((ext_vector_type(2)));
typedef __bf16 bf16x8 __attribute__((ext_vector_type(8)));
typedef unsigned short us4 __attribute__((ext_vector_type(4)));

#define B_ 8
#define L_ 4096
#define D_ 384
#define DI_ 768
#define S_ 16
#define NC_ 40
#define ML_ (B_*L_)   // 32768 rows
#define NCHUNK 32
#define CL 128        // chunk length (L_/NCHUNK)

// ---------------- workspace layout (bytes) ----------------
// ~154 MB total. Aliasing:
//   XN lives in XC region (dead after gemm1, before conv writes XC);
//   XDBL lives at start of XP region (XP dead after conv);
//   FX (chunk summaries, 38.5 MB) lives in XP region after XDBL.
constexpr size_t au(size_t x){ return (x + 255) & ~size_t(255); }
constexpr size_t O_FLAG = 0;                                   // int
constexpr size_t O_LNW  = 256;                                 // 384 f32
constexpr size_t O_CONVW= au(O_LNW  + 384*4);                  // 3072 f32
constexpr size_t O_CONVB= au(O_CONVW+ 3072*4);                 // 768 f32
constexpr size_t O_WDT  = au(O_CONVB+ 768*4);                  // 18432 f32
constexpr size_t O_DTB  = au(O_WDT  + 18432*4);                // 768 f32
constexpr size_t O_A    = au(O_DTB  + 768*4);                  // 12288 f32 (A = -exp(A_log)*log2e)
constexpr size_t O_DSKIP= au(O_A    + 12288*4);                // 768 f32
constexpr size_t O_WOUT = au(O_DSKIP+ 768*4);                  // 294912 f32
constexpr size_t O_WFC  = au(O_WOUT + 294912*4);               // 98304 f32
constexpr size_t O_BFC  = au(O_WFC  + 98304*4);                // 256 f32
constexpr size_t O_GAM  = au(O_BFC  + 256*4);
constexpr size_t O_BET  = au(O_GAM  + 256*4);
constexpr size_t O_WCLS = au(O_BET  + 256*4);                  // 10240 f32
constexpr size_t O_BCLS = au(O_WCLS + 10240*4);                // 40 f32
constexpr size_t O_XMEAN= au(O_BCLS + 40*4);                   // 8*384 f32 (atomic acc; later sP in-place)
constexpr size_t O_YMEAN= au(O_XMEAN+ 3072*4);                 // 8*768 f32
constexpr size_t O_H    = au(O_YMEAN+ 6144*4);                 // 8*256 f32
constexpr size_t O_WINT = au(O_H    + 2048*4);                 // W_in^T  [1536][384] bf16
constexpr size_t O_WXT  = au(O_WINT + (size_t)589824*2);       // W_xproj^T padded [64][768] bf16
constexpr size_t O_XP   = au(O_WXT  + (size_t)49152*2);        // [32768][768] bf16
constexpr size_t O_XDBL = O_XP;                                // alias: [32768][56] f32 (after conv)
constexpr size_t O_FX   = au(O_XDBL + (size_t)ML_*56*4);       // [b][c][49][768] f32 chunk summaries
constexpr size_t FX_SZ  = (size_t)B_*NCHUNK*49*768*4;          // 38.5 MB
constexpr size_t O_Z    = au(O_XP   + (size_t)ML_*768*2);      // [32768][768] bf16 (holds silu(z))
constexpr size_t O_XCU  = au(O_Z    + (size_t)ML_*768*2);      // union region, 50.3 MB
constexpr size_t O_XN   = O_XCU;                               // [32768][384] bf16 (dead after gemm1)
constexpr size_t O_XC   = O_XCU;                               // [32768][768] bf16
constexpr size_t WS_NEED= O_XCU + (size_t)ML_*768*2;           // ~154 MB
static_assert(O_FX + FX_SZ <= O_Z, "FX must fit in dead XP tail");

// ---------------- helpers ----------------
__device__ inline float bf2f(ushort_t u){ return __uint_as_float(((u32)u) << 16); }
__device__ inline ushort_t f2bf(float f){
    u32 x = __float_as_uint(f);
    u32 r = (x + 0x7fffu + ((x >> 16) & 1u)) >> 16;   // RNE
    return (ushort_t)r;
}
__device__ inline float ldf(const void* p, long i, int flag){
    return flag ? bf2f(((const ushort_t*)p)[i]) : ((const float*)p)[i];
}
__device__ inline ushort_t ldbf(const void* p, long i, int flag){
    return flag ? ((const ushort_t*)p)[i] : f2bf(((const float*)p)[i]);
}
__device__ inline float sigm(float v){ return 1.f / (1.f + __expf(-v)); }

__device__ inline void gload_lds16(const void* g, void* l){
    __builtin_amdgcn_global_load_lds(
        (const __attribute__((address_space(1))) u32*)g,
        (__attribute__((address_space(3))) u32*)l, 16, 0, 0);
}

struct Ptrs { const void* p[17]; };

// ---------------- k0: dtype detect ----------------
__global__ void k_detect(const void* x, char* ws){
    __shared__ float s[256];
    int tid = threadIdx.x;
    s[tid] = fabsf(bf2f(((const ushort_t*)x)[tid]));
    __syncthreads();
    for (int st = 128; st > 0; st >>= 1){
        if (tid < st) s[tid] = fmaxf(s[tid], s[tid + st]);
        __syncthreads();
    }
    if (tid == 0) *(int*)(ws + O_FLAG) = (s[0] < 1e4f) ? 1 : 0;
}

// ---------------- k1: weight prep ----------------
#define N_PREP 1082792L
__global__ __launch_bounds__(256) void k_prep(Ptrs ps, char* ws){
    const int flag = *(const int*)(ws + O_FLAG);
    long o = (long)blockIdx.x * 256 + threadIdx.x;
    if (o < 384){ ((float*)(ws+O_LNW))[o]  = ldf(ps.p[1],o,flag); return; }  o -= 384;
    if (o < 3072){ ((float*)(ws+O_CONVW))[o]= ldf(ps.p[3],o,flag); return; } o -= 3072;
    if (o < 768){ ((float*)(ws+O_CONVB))[o]= ldf(ps.p[4],o,flag); return; }  o -= 768;
    if (o < 18432){ ((float*)(ws+O_WDT))[o]= ldf(ps.p[6],o,flag); return; }  o -= 18432;
    if (o < 768){ ((float*)(ws+O_DTB))[o]  = ldf(ps.p[7],o,flag); return; }  o -= 768;
    if (o < 768){ ((float*)(ws+O_DSKIP))[o]= ldf(ps.p[9],o,flag); return; }  o -= 768;
    if (o < 294912){ ((float*)(ws+O_WOUT))[o]= ldf(ps.p[10],o,flag); return; } o -= 294912;
    if (o < 98304){ ((float*)(ws+O_WFC))[o]= ldf(ps.p[11],o,flag); return; } o -= 98304;
    if (o < 256){ ((float*)(ws+O_BFC))[o]  = ldf(ps.p[12],o,flag); return; } o -= 256;
    if (o < 256){ ((float*)(ws+O_GAM))[o]  = ldf(ps.p[13],o,flag); return; } o -= 256;
    if (o < 256){ ((float*)(ws+O_BET))[o]  = ldf(ps.p[14],o,flag); return; } o -= 256;
    if (o < 10240){ ((float*)(ws+O_WCLS))[o]= ldf(ps.p[15],o,flag); return; } o -= 10240;
    if (o < 40){ ((float*)(ws+O_BCLS))[o]  = ldf(ps.p[16],o,flag); return; } o -= 40;
    // A = -exp(A_log) * log2(e)   (scan uses exp2)
    if (o < 12288){ ((float*)(ws+O_A))[o]  = -__expf(ldf(ps.p[8],o,flag)) * 1.4426950408889634f; return; } o -= 12288;
    if (o < 589824){                     // W_in [384,1536] -> WinT [1536][384]
        long n = o / 384, k = o % 384;
        ((ushort_t*)(ws+O_WINT))[o] = ldbf(ps.p[2], k*1536 + n, flag); return;
    } o -= 589824;
    if (o < 49152){                      // W_xproj [768,56] -> WxT [64][768], zero-pad n>=56
        long n = o / 768, k = o % 768;
        ((ushort_t*)(ws+O_WXT))[o] = (n < 56) ? ldbf(ps.p[5], k*56 + n, flag) : (ushort_t)0;
        return;
    } o -= 49152;
    if (o < 3072){ ((float*)(ws+O_XMEAN))[o] = 0.f; return; }
}

// ---------------- k2: fused RMSNorm + xmean ----------------
__global__ __launch_bounds__(256) void k_rmsxm(const void* x, char* ws){
    const int flag = *(const int*)(ws + O_FLAG);
    const float* lnw = (const float*)(ws + O_LNW);
    ushort_t* xn = (ushort_t*)(ws + O_XN);
    float* xmean = (float*)(ws + O_XMEAN);
    int tid = threadIdx.x;
    int lane = tid & 63, w = tid >> 6;
    long row0 = (long)blockIdx.x * 16 + w * 4;
    int b = blockIdx.x >> 8;                   // 256 blocks per batch
    float lw[6];
    #pragma unroll
    for (int k = 0; k < 6; k++) lw[k] = lnw[lane + k*64];
    float xacc[6] = {0.f,0.f,0.f,0.f,0.f,0.f};
    for (int i = 0; i < 4; i++){
        long row = row0 + i;
        float v[6];
        if (flag){
            const ushort_t* xb = (const ushort_t*)x + row*384;
            #pragma unroll
            for (int k = 0; k < 6; k++) v[k] = bf2f(xb[lane + k*64]);
        } else {
            const float* xf = (const float*)x + row*384;
            #pragma unroll
            for (int k = 0; k < 6; k++) v[k] = xf[lane + k*64];
        }
        float ss = 0.f;
        #pragma unroll
        for (int k = 0; k < 6; k++) ss += v[k]*v[k];
        #pragma unroll
        for (int m = 1; m < 64; m <<= 1) ss += __shfl_xor(ss, m);
        float scale = rsqrtf(ss * (1.f/384.f) + 1e-5f);
        #pragma unroll
        for (int k = 0; k < 6; k++){
            xn[row*384 + lane + k*64] = f2bf(v[k] * scale * lw[k]);
            xacc[k] += v[k];
        }
    }
    __shared__ float part[4][384];
    #pragma unroll
    for (int k = 0; k < 6; k++) part[w][lane + k*64] = xacc[k];
    __syncthreads();
    for (int d = tid; d < 384; d += 256){
        float s = part[0][d] + part[1][d] + part[2][d] + part[3][d];
        atomicAdd(&xmean[b*384 + d], s * (1.f/L_));
    }
}

// ---------------- k4: GEMM1  xn @ W_in -> xp | silu(z) ---------
// R9: grid transposed to (12, 256) n-fastest. Old x=m-fastest put the 12
// reuses of each A-panel 256 dispatches apart on the SAME XCD (256%8==0)
// with ~6MB traffic between -> L2-evicted, A refetched from L3 12x
// (~300 MB). Now the 12 reuses are consecutive (~2.3MB window, L2-hot);
// B-panels cycle on a fixed 2-XCD orbit and stay hot.
__global__ __launch_bounds__(256) void k_gemm1(char* ws){
    const ushort_t* xn = (const ushort_t*)(ws + O_XN);
    const ushort_t* wT = (const ushort_t*)(ws + O_WINT);
    ushort_t* xp = (ushort_t*)(ws + O_XP);
    ushort_t* zz = (ushort_t*)(ws + O_Z);
    __shared__ ushort_t sA[128*32];
    __shared__ ushort_t sB[128*32];
    int tid = threadIdx.x, w = tid >> 6, l = tid & 63;
    long m0 = (long)blockIdx.y * 128;
    int n0 = blockIdx.x * 128;
    f32x4 acc[4][4] = {};
    int lr = l >> 2, lk = (l & 3) * 8;
    const ushort_t* gA = xn + (m0 + w*16 + lr)*384 + lk;
    const ushort_t* gB = wT + ((long)(n0 + w*16 + lr))*384 + lk;
    ushort_t* lA = &sA[w*16*32];
    ushort_t* lB = &sB[w*16*32];
    int wm = w & 1, wn = w >> 1;
    int arow = wm*64 + (l & 15);
    int brow = wn*64 + (l & 15);
    int koff = (l >> 4) * 8;
    for (int kc = 0; kc < 12; kc++){
        int k0 = kc * 32;
        gload_lds16(gA + k0,           lA);
        gload_lds16(gA + k0 + 64*384,  lA + 64*32);
        gload_lds16(gB + k0,           lB);
        gload_lds16(gB + k0 + 64*384,  lB + 64*32);
        __syncthreads();
        bf16x8 af[4], bfv[4];
        #pragma unroll
        for (int i = 0; i < 4; i++){
            af[i]  = *(const bf16x8*)&sA[(arow + i*16)*32 + koff];
            bfv[i] = *(const bf16x8*)&sB[(brow + i*16)*32 + koff];
        }
        #pragma unroll
        for (int mb = 0; mb < 4; mb++)
            #pragma unroll
            for (int nb = 0; nb < 4; nb++)
                acc[mb][nb] = __builtin_amdgcn_mfma_f32_16x16x32_bf16(bfv[nb], af[mb], acc[mb][nb], 0, 0, 0);
        __syncthreads();
    }
    ushort_t* outp; int nc0; bool isz;
    if (n0 < 768){ outp = xp; nc0 = n0; isz = false; }
    else { outp = zz; nc0 = n0 - 768; isz = true; }
    int cl = l & 15, rb4 = (l >> 4) * 4;
    #pragma unroll
    for (int mb = 0; mb < 4; mb++)
        #pragma unroll
        for (int nb = 0; nb < 4; nb++){
            long row = m0 + wm*64 + mb*16 + cl;
            int col = nc0 + wn*64 + nb*16 + rb4;
            us4 o;
            #pragma unroll
            for (int r = 0; r < 4; r++){
                float v = acc[mb][nb][r];
                if (isz) v = v * sigm(v);        // fused silu for z
                o[r] = f2bf(v);
            }
            *(us4*)&outp[row*768 + col] = o;
        }
}

// ---------------- k5: causal depthwise conv K=4 + SiLU, vec4 ----------------
__global__ __launch_bounds__(192) void k_conv(char* ws){
    const ushort_t* xp = (const ushort_t*)(ws + O_XP);
    ushort_t* xc = (ushort_t*)(ws + O_XC);
    const float* cw = (const float*)(ws + O_CONVW);
    const float* cb = (const float*)(ws + O_CONVB);
    int d0 = threadIdx.x * 4;
    int t0 = blockIdx.y * 8;
    int b = blockIdx.z;
    long rbase = (long)b * L_;
    f32x4 w0, w1, w2, w3, bias;
    #pragma unroll
    for (int c = 0; c < 4; c++){
        w0[c] = cw[(d0+c)*4+0]; w1[c] = cw[(d0+c)*4+1];
        w2[c] = cw[(d0+c)*4+2]; w3[c] = cw[(d0+c)*4+3];
        bias[c] = cb[d0+c];
    }
    f32x4 xv[11];
    #pragma unroll
    for (int i = 0; i < 11; i++){
        int t = t0 - 3 + i;
        if (t >= 0){
            us4 v = *(const us4*)&xp[(rbase + t)*768 + d0];
            #pragma unroll
            for (int c = 0; c < 4; c++) xv[i][c] = bf2f(v[c]);
        } else {
            xv[i] = f32x4{0.f, 0.f, 0.f, 0.f};
        }
    }
    #pragma unroll
    for (int tt = 0; tt < 8; tt++){
        f32x4 v = bias + xv[tt]*w0 + xv[tt+1]*w1 + xv[tt+2]*w2 + xv[tt+3]*w3;
        us4 o;
        #pragma unroll
        for (int c = 0; c < 4; c++){
            float s = v[c] * sigm(v[c]);
            o[c] = f2bf(s);
        }
        *(us4*)&xc[(rbase + t0 + tt)*768 + d0] = o;
    }
}

// ---------------- k6: xproj  xc @ W_xproj -> x_dbl[32768,56] ----
// R9: M-tile 128 -> 64. Old grid was 256 blocks = 1 block/CU: 24 serial
// K-chunks x 2 barriers with only 4 waves resident -> every barrier drain
// exposed. Now 512 blocks = 2/CU, half the serial work per block, LDS
// 12KB -> 8KB. Each wave computes 16 rows (acc[4]), stages 16 rows of A.
__global__ __launch_bounds__(256) void k_xproj(char* ws){
    const ushort_t* xc = (const ushort_t*)(ws + O_XC);
    const ushort_t* wT = (const ushort_t*)(ws + O_WXT);
    float* xdbl = (float*)(ws + O_XDBL);
    __shared__ ushort_t sA[64*32];
    __shared__ ushort_t sB[64*32];
    int tid = threadIdx.x, w = tid >> 6, l = tid & 63;
    long m0 = (long)blockIdx.x * 64;
    f32x4 acc[4] = {};
    int lr = l >> 2, lk = (l & 3) * 8;
    const ushort_t* gA = xc + (m0 + w*16 + lr)*768 + lk;
    const ushort_t* gB = wT + ((long)(w*16 + lr))*768 + lk;
    ushort_t* lA = &sA[w*16*32];
    ushort_t* lB = &sB[w*16*32];
    int arow0 = w*16 + (l & 15);
    int brow = l & 15;
    int koff = (l >> 4) * 8;
    for (int kc = 0; kc < 24; kc++){
        int k0 = kc * 32;
        gload_lds16(gA + k0, lA);
        gload_lds16(gB + k0, lB);
        __syncthreads();
        bf16x8 af, bfv[4];
        af = *(const bf16x8*)&sA[arow0*32 + koff];
        #pragma unroll
        for (int nb = 0; nb < 4; nb++)
            bfv[nb] = *(const bf16x8*)&sB[(nb*16 + brow)*32 + koff];
        #pragma unroll
        for (int nb = 0; nb < 4; nb++)
            acc[nb] = __builtin_amdgcn_mfma_f32_16x16x32_bf16(bfv[nb], af, acc[nb], 0, 0, 0);
        __syncthreads();
    }
    int cl = l & 15, rb4 = (l >> 4) * 4;
    #pragma unroll
    for (int nb = 0; nb < 4; nb++){
        int nbase = nb*16 + rb4;
        if (nbase < 56){
            long row = m0 + w*16 + cl;
            *(f32x4*)&xdbl[row*56 + nbase] = acc[nb];
        }
    }
}

// ---------------- k7: chunk-parallel selective scan (pass 1) --------------
// v10 (unchanged; issue-bound at ~144us, parked — see R6 note).
__global__ __launch_bounds__(256, 3) void k_scan(char* ws){
    const ushort_t* xc = (const ushort_t*)(ws + O_XC);
    const ushort_t* wz = (const ushort_t*)(ws + O_Z);      // silu(z)
    const float* xdbl = (const float*)(ws + O_XDBL);
    const float* Ag = (const float*)(ws + O_A);            // -exp(A_log)*log2e
    const float* Dsk = (const float*)(ws + O_DSKIP);
    const float* Wdt = (const float*)(ws + O_WDT);
    const float* dtb = (const float*)(ws + O_DTB);
    float* FX = (float*)(ws + O_FX);
    int tid = threadIdx.x;
    int half = tid & 1, p = tid >> 1;          // pair = lanes 2k,2k+1; 128 pairs
    int d = blockIdx.x * 256 + p;              // channel A; channel B = d+128
    int c = blockIdx.y, b = blockIdx.z;
    long row0 = (long)b * L_ + (long)c * CL;

    __shared__ float sXD[CL*56];               // 28 KB: whole chunk's xdbl
    {
        const f32x4* src = (const f32x4*)(xdbl + row0*56);   // 1792 vec4
        f32x4* dst = (f32x4*)sXD;
        #pragma unroll
        for (int i = 0; i < 7; i++) dst[tid + i*256] = src[tid + i*256];
    }

    f32x2 wdtA[6], wdtB[6];
    #pragma unroll
    for (int k = 0; k < 6; k++){
        wdtA[k][0] = Wdt[(half*12 + 2*k    )*768 + d];
        wdtA[k][1] = Wdt[(half*12 + 2*k + 1)*768 + d];
        wdtB[k][0] = Wdt[(half*12 + 2*k    )*768 + d + 128];
        wdtB[k][1] = Wdt[(half*12 + 2*k + 1)*768 + d + 128];
    }
    float dbiasA = half ? 0.f : dtb[d];
    float dbiasB = half ? 0.f : dtb[d + 128];
    f32x2 AvA[4], AvB[4];
    #pragma unroll
    for (int j = 0; j < 4; j++){
        AvA[j][0] = Ag[d*16 + half*8 + 2*j];
        AvA[j][1] = Ag[d*16 + half*8 + 2*j + 1];
        AvB[j][0] = Ag[(d+128)*16 + half*8 + 2*j];
        AvB[j][1] = Ag[(d+128)*16 + half*8 + 2*j + 1];
    }
    float DvA = Dsk[d], DvB = Dsk[d + 128];
    __syncthreads();                           // the only barrier

    f32x2 hA[4], qA[4], GA[4], hB[4], qB[4], GB[4];
    #pragma unroll
    for (int j = 0; j < 4; j++){
        hA[j] = f32x2{0.f,0.f}; GA[j] = f32x2{0.f,0.f}; qA[j] = f32x2{1.f,1.f};
        hB[j] = f32x2{0.f,0.f}; GB[j] = f32x2{0.f,0.f}; qB[j] = f32x2{1.f,1.f};
    }
    f32x2 ysA2 = {0.f,0.f}, ysB2 = {0.f,0.f};
    float sdwA = 0.f, sdwB = 0.f;

    const ushort_t* gx = (half ? wz : xc) + row0*768 + d;   // parity-split stream

    #pragma unroll 4
    for (int t = 0; t < CL; t++){
        ushort_t mA = gx[t*768];
        ushort_t mB = gx[t*768 + 128];
        const float* xd = &sXD[t*56];
        // dt dot for both channels — xd vec4 loads shared
        f32x2 accA = {dbiasA, 0.f}, accB = {dbiasB, 0.f};
        #pragma unroll
        for (int j = 0; j < 3; j++){
            f32x4 v = *(const f32x4*)&xd[half*12 + j*4];
            f32x2 vlo = {v[0], v[1]}, vhi = {v[2], v[3]};
            accA += vlo * wdtA[2*j];  accA += vhi * wdtA[2*j + 1];
            accB += vlo * wdtB[2*j];  accB += vhi * wdtB[2*j + 1];
        }
        float dpA = accA[0] + accA[1], dpB = accB[0] + accB[1];
        float dtA = dpA + __shfl_xor(dpA, 1);
        float dtB = dpB + __shfl_xor(dpB, 1);
        // softplus both
        float eA = __builtin_amdgcn_exp2f(dtA * 1.4426950408889634f);
        float sA_ = 0.69314718055994531f * __builtin_amdgcn_logf(1.f + eA);
        dtA = (dtA > 20.f) ? dtA : sA_;
        float eB = __builtin_amdgcn_exp2f(dtB * 1.4426950408889634f);
        float sB_ = 0.69314718055994531f * __builtin_amdgcn_logf(1.f + eB);
        dtB = (dtB > 20.f) ? dtB : sB_;
        // packed xc/z exchange for both channels in ONE shuffle
        u32 pk = (u32)mA | ((u32)mB << 16);
        u32 other = (u32)__shfl_xor((int)pk, 1);
        ushort_t oA = (ushort_t)(other & 0xffffu), oB = (ushort_t)(other >> 16);
        float xcvA = bf2f(half ? oA : mA);
        float wzvA = bf2f(half ? mA : oA);
        float xcvB = bf2f(half ? oB : mB);
        float wzvB = bf2f(half ? mB : oB);
        float uA = dtA * xcvA, uB = dtB * xcvB;
        f32x2 uA2 = {uA,uA}, uB2 = {uB,uB};
        f32x2 wzA2 = {wzvA,wzvA}, wzB2 = {wzvB,wzvB};
        f32x2 dtA2 = {dtA,dtA}, dtB2 = {dtB,dtB};
        // B/C vec4 loads shared between channels (same t, same s-range)
        f32x4 Bva = *(const f32x4*)&xd[24 + half*8];
        f32x4 Bvb = *(const f32x4*)&xd[28 + half*8];
        f32x4 Cva = *(const f32x4*)&xd[40 + half*8];
        f32x4 Cvb = *(const f32x4*)&xd[44 + half*8];
        #pragma unroll
        for (int j = 0; j < 4; j++){
            f32x2 Bj = (j < 2) ? f32x2{Bva[2*j], Bva[2*j+1]} : f32x2{Bvb[2*j-4], Bvb[2*j-3]};
            f32x2 Cj = (j < 2) ? f32x2{Cva[2*j], Cva[2*j+1]} : f32x2{Cvb[2*j-4], Cvb[2*j-3]};
            // channel A
            f32x2 argA = dtA2 * AvA[j];
            f32x2 dAA;
            dAA[0] = __builtin_amdgcn_exp2f(argA[0]);
            dAA[1] = __builtin_amdgcn_exp2f(argA[1]);
            hA[j] = dAA * hA[j] + uA2 * Bj;
            f32x2 CwA = Cj * wzA2;
            ysA2 += hA[j] * CwA;
            qA[j] = qA[j] * dAA;
            GA[j] += qA[j] * CwA;
            // channel B
            f32x2 argB = dtB2 * AvB[j];
            f32x2 dAB;
            dAB[0] = __builtin_amdgcn_exp2f(argB[0]);
            dAB[1] = __builtin_amdgcn_exp2f(argB[1]);
            hB[j] = dAB * hB[j] + uB2 * Bj;
            f32x2 CwB = Cj * wzB2;
            ysB2 += hB[j] * CwB;
            qB[j] = qB[j] * dAB;
            GB[j] += qB[j] * CwB;
        }
        sdwA += xcvA * wzvA;
        sdwB += xcvB * wzvB;
    }
    float ysA = ysA2[0] + ysA2[1] + (half ? 0.f : DvA * sdwA);
    float ysB = ysB2[0] + ysB2[1] + (half ? 0.f : DvB * sdwB);
    ysA += __shfl_xor(ysA, 1);
    ysB += __shfl_xor(ysB, 1);
    long fbA = ((long)(b*NCHUNK + c)*49)*768 + d;
    long fbB = fbA + 128;
    if (!half){ FX[fbA] = ysA; FX[fbB] = ysB; }
    #pragma unroll
    for (int j = 0; j < 4; j++){
        int sg = half*8 + 2*j;
        FX[fbA + (1+sg)*768]  = hA[j][0];  FX[fbA + (2+sg)*768]  = hA[j][1];
        FX[fbA + (17+sg)*768] = qA[j][0];  FX[fbA + (18+sg)*768] = qA[j][1];
        FX[fbA + (33+sg)*768] = GA[j][0];  FX[fbA + (34+sg)*768] = GA[j][1];
        FX[fbB + (1+sg)*768]  = hB[j][0];  FX[fbB + (2+sg)*768]  = hB[j][1];
        FX[fbB + (17+sg)*768] = qB[j][0];  FX[fbB + (18+sg)*768] = qB[j][1];
        FX[fbB + (33+sg)*768] = GB[j][0];  FX[fbB + (34+sg)*768] = GB[j][1];
    }
}

// ---------------- k8: scan pass 2 — stitch chunks (thread per (b,d,s)) ----
__global__ __launch_bounds__(256) void k_fix(char* ws){
    const float* FX = (const float*)(ws + O_FX);
    float* ymean = (float*)(ws + O_YMEAN);
    int tid = threadIdx.x;
    int dl = tid & 15, s = tid >> 4;
    int d = blockIdx.x * 16 + dl;
    int b = blockIdx.y;
    float Hrun = 0.f, ys = 0.f;
    for (int c = 0; c < NCHUNK; c++){
        long fb = ((long)(b*NCHUNK + c)*49)*768 + d;
        float Gs = FX[fb + (33+s)*768];
        float Hs = FX[fb + (1+s)*768];
        float qs = FX[fb + (17+s)*768];
        ys += Hrun * Gs;
        if (s == 0) ys += FX[fb];
        Hrun = Hs + qs * Hrun;
    }
    __shared__ float sR[256];
    sR[tid] = ys;
    __syncthreads();
    #pragma unroll
    for (int st = 8; st >= 1; st >>= 1){
        if (s < st) sR[tid] += sR[tid + st*16];
        __syncthreads();
    }
    if (s == 0) ymean[b*768 + d] = sR[dl] * (1.f/L_);
}

// ---------------- k9a: sP = xmean + ymean @ Wout  (in-place into xmean) ---
__global__ __launch_bounds__(256) void k_head1a(char* ws){
    const float* ymean = (const float*)(ws + O_YMEAN);
    const float* Wout = (const float*)(ws + O_WOUT);
    float* xmean = (float*)(ws + O_XMEAN);     // becomes sP
    int b = blockIdx.x;
    int d = blockIdx.y*128 + (threadIdx.x >> 1);
    int half = threadIdx.x & 1;
    const float* ym = ymean + b*768 + half*384;
    const float* wo = Wout + (long)half*384*384 + d;
    float acc = 0.f;
    #pragma unroll 8
    for (int i = 0; i < 384; i++)
        acc += ym[i] * wo[i*384];
    acc += __shfl_xor(acc, 1);
    if (!half) xmean[b*384 + d] += acc;
}

// ---------------- k9b: h = sP @ W_fc + b_fc ------------------------------
__global__ __launch_bounds__(256) void k_head1(char* ws){
    const float* sP = (const float*)(ws + O_XMEAN);
    const float* Wfc = (const float*)(ws + O_WFC);
    const float* bfc = (const float*)(ws + O_BFC);
    float* hbuf = (float*)(ws + O_H);
    int b = blockIdx.x, tid = threadIdx.x;
    __shared__ float sPl[384];
    for (int i = tid; i < 384; i += 256) sPl[i] = sP[b*384 + i];
    __syncthreads();
    float v = bfc[tid];
    #pragma unroll 8
    for (int dd = 0; dd < 384; dd++) v += sPl[dd] * Wfc[dd*256 + tid];
    hbuf[b*256 + tid] = v;
}

// ---------------- k10: head part 2: batchnorm + relu + classifier --------
__global__ __launch_bounds__(384) void k_head2(char* ws, void* out){
    const int flag = *(const int*)(ws + O_FLAG);
    const float* hbuf = (const float*)(ws + O_H);
    const float* gam = (const float*)(ws + O_GAM);
    const float* bet = (const float*)(ws + O_BET);
    const float* Wcls = (const float*)(ws + O_WCLS);
    const float* bcls = (const float*)(ws + O_BCLS);
    int tid = threadIdx.x;
    __shared__ float sH[8*256];
    if (tid < 256){
        float hv[8]; float mu = 0.f;
        #pragma unroll
        for (int b = 0; b < 8; b++){ hv[b] = hbuf[b*256 + tid]; mu += hv[b]; }
        mu *= 0.125f;
        float var = 0.f;
        #pragma unroll
        for (int b = 0; b < 8; b++){ float dv = hv[b]-mu; var += dv*dv; }
        var *= 0.125f;
        float rs = rsqrtf(var + 1e-5f);
        #pragma unroll
        for (int b = 0; b < 8; b++){
            float t = (hv[b]-mu)*rs*gam[tid] + bet[tid];
            sH[b*256 + tid] = t > 0.f ? t : 0.f;
        }
    }
    __syncthreads();
    if (tid < 320){
        int b = tid / 40, c = tid % 40;
        float acc = bcls[c];
        for (int j = 0; j < 256; j++) acc += sH[b*256 + j] * Wcls[j*40 + c];
        if (flag) ((ushort_t*)out)[b*40 + c] = f2bf(acc);
        else      ((float*)out)[b*40 + c] = acc;
    }
}

// ---------------- launch ----------------
extern "C" void kernel_launch(void* const* d_in, const int* in_sizes, int n_in,
                              void* d_out, int out_size, void* d_ws, size_t ws_size,
                              hipStream_t stream){
    (void)in_sizes; (void)n_in; (void)out_size; (void)ws_size;
    char* ws = (char*)d_ws;
    Ptrs ps;
    for (int i = 0; i < 17; i++) ps.p[i] = d_in[i];

    k_detect<<<1, 256, 0, stream>>>(d_in[0], ws);
    k_prep<<<(unsigned)((N_PREP + 255) / 256), 256, 0, stream>>>(ps, ws);
    k_rmsxm<<<ML_/16, 256, 0, stream>>>(d_in[0], ws);
    k_gemm1<<<dim3(12, ML_/128), 256, 0, stream>>>(ws);
    k_conv<<<dim3(1, L_/8, B_), 192, 0, stream>>>(ws);
    k_xproj<<<ML_/64, 256, 0, stream>>>(ws);
    k_scan<<<dim3(3, NCHUNK, B_), 256, 0, stream>>>(ws);
    k_fix<<<dim3(48, B_), 256, 0, stream>>>(ws);
    k_head1a<<<dim3(8, 3), 256, 0, stream>>>(ws);
    k_head1<<<B_, 256, 0, stream>>>(ws);
    k_head2<<<1, 384, 0, stream>>>(ws, d_out);
}